// Round 10
// baseline (470.625 us; speedup 1.0000x reference)
//
#include <hip/hip_runtime.h>
#include <hip/hip_bf16.h>
#include <math.h>

// Problem constants
#define BB 8
#define NSEQ 1024
#define EMB 768
#define HEADS 8
#define INNER 96
#define HEAD_D 12
#define MLP_DIM 3072
#define ROWS (BB * NSEQ)   // 8192

using short8  = __attribute__((ext_vector_type(8))) short;
using s4b     = __attribute__((ext_vector_type(4))) short;
using floatx4 = __attribute__((ext_vector_type(4))) float;

static __device__ __forceinline__ ushort f2b(float x) {
    __hip_bfloat16 h = __float2bfloat16(x);
    return *reinterpret_cast<ushort*>(&h);
}
static __device__ __forceinline__ uint pk2(float a, float b) {
    return (uint)f2b(a) | ((uint)f2b(b) << 16);
}

// 16x16x16 bf16 MFMA (a,b: 4 bf16 = 2 VGPR; c/d: 4 f32)
static __device__ __forceinline__ floatx4 mfma16(s4b a, s4b b, floatx4 c) {
#if __has_builtin(__builtin_amdgcn_mfma_f32_16x16x16_bf16)
    return __builtin_amdgcn_mfma_f32_16x16x16_bf16(a, b, c, 0, 0, 0);
#elif __has_builtin(__builtin_amdgcn_mfma_f32_16x16x16bf16_1k)
    return __builtin_amdgcn_mfma_f32_16x16x16bf16_1k(a, b, c, 0, 0, 0);
#else
    floatx4 d;
    asm("v_mfma_f32_16x16x16_bf16 %0, %1, %2, %3" : "=v"(d) : "v"(a), "v"(b), "v"(c));
    return d;
#endif
}
#define MFMA32(a, b, c) __builtin_amdgcn_mfma_f32_16x16x32_bf16((a), (b), (c), 0, 0, 0)

static __device__ __forceinline__ float gelu_f(float v) {
    // tanh-GELU via sigmoid; |err| ~3e-4 << bf16 rounding.
    float u = v * (1.0f + 0.044715f * v * v);
    return v / (1.0f + __expf(-1.5957691216057308f * u));
}

// ---------------------------------------------------------------------------
// LayerNorm: one wave per row of 768, bf16 output. 4 rows / 256-thr block.
// ---------------------------------------------------------------------------
__global__ __launch_bounds__(256) void ln_bf16_kernel(const float* __restrict__ x,
                                                      const float* __restrict__ g,
                                                      const float* __restrict__ b,
                                                      ushort* __restrict__ out) {
    int row  = blockIdx.x * 4 + (threadIdx.x >> 6);
    int lane = threadIdx.x & 63;
    const float* xr = x + (size_t)row * EMB;
    float v[12];
    float s = 0.f;
#pragma unroll
    for (int i = 0; i < 12; i++) {
        v[i] = xr[lane + i * 64];
        s += v[i];
    }
#pragma unroll
    for (int off = 32; off; off >>= 1) s += __shfl_xor(s, off);
    float mu = s * (1.0f / EMB);
    float ss = 0.f;
#pragma unroll
    for (int i = 0; i < 12; i++) { float d = v[i] - mu; ss += d * d; }
#pragma unroll
    for (int off = 32; off; off >>= 1) ss += __shfl_xor(ss, off);
    float rstd = rsqrtf(ss * (1.0f / EMB) + 1e-5f);
    ushort* orow = out + (size_t)row * EMB;
#pragma unroll
    for (int i = 0; i < 12; i++) {
        int c = lane + i * 64;
        orow[c] = f2b((v[i] - mu) * rstd * g[c] + b[c]);
    }
}

// ---------------------------------------------------------------------------
// Weight convert+transpose: out[n][k] = bf16(in[k][n]); n in [0,Npad),
// zeros for n >= N. 32x32 tiles via LDS.
// ---------------------------------------------------------------------------
__global__ __launch_bounds__(256) void convt_kernel(const float* __restrict__ in,
                                                    ushort* __restrict__ out,
                                                    int K, int N, int Npad) {
    __shared__ float t[32][33];
    int n0 = blockIdx.x * 32, k0 = blockIdx.y * 32;
    int tx = threadIdx.x, ty = threadIdx.y;
#pragma unroll
    for (int i = 0; i < 32; i += 8) {
        int n = n0 + tx;
        t[ty + i][tx] = (n < N) ? in[(size_t)(k0 + ty + i) * N + n] : 0.f;
    }
    __syncthreads();
#pragma unroll
    for (int i = 0; i < 32; i += 8) {
        out[(size_t)(n0 + ty + i) * K + k0 + tx] = f2b(t[tx][ty + i]);
    }
}

// Variant padding K: out[n][k] for k in [0,Kpad), zero for k >= K.
__global__ __launch_bounds__(256) void convt_pad_kernel(const float* __restrict__ in,
                                                        ushort* __restrict__ out,
                                                        int K, int N, int Kpad) {
    __shared__ float t[32][33];
    int n0 = blockIdx.x * 32, k0 = blockIdx.y * 32;
    int tx = threadIdx.x, ty = threadIdx.y;
#pragma unroll
    for (int i = 0; i < 32; i += 8) {
        int k = k0 + ty + i;
        t[ty + i][tx] = (k < K) ? in[(size_t)k * N + n0 + tx] : 0.f;
    }
    __syncthreads();
#pragma unroll
    for (int i = 0; i < 32; i += 8) {
        out[(size_t)(n0 + ty + i) * Kpad + k0 + tx] = f2b(t[tx][ty + i]);
    }
}

// ---------------------------------------------------------------------------
// LDS-FREE streamed MFMA GEMM: C[M,Nn] = A[M,K](bf16) @ Bt[Npad,K](bf16)^T.
// 128x128 tile, 4 waves (2x2), per-wave 64x64. Both operands stream
// global(L1/L2)->VGPR: each lane reads the SAME logical 16B fragment chunks
// the LDS path used (A[row][k0+ c*8], row=...+qr, c=ks*4+grp) — no LDS, no
// barriers, no staging. Register double-buffer (even/odd named sets,
// hand-pipelined over t,t+1) hides L2 latency; 2 waves/SIMD TLP covers rest.
// Wave-pair duplicate reads hit L1; XCD swizzle (T1) keeps panels L2-hot.
// Requires K%128==0 is NOT needed; nt=K/64 must be EVEN (all our K: 768->12,
// 128->2, 3072->48). gridDim.x%8==0.
// ---------------------------------------------------------------------------
template <int EPI, bool MASKN>
__global__ __launch_bounds__(256) void gemm_stream(const ushort* __restrict__ A,
                                                   const ushort* __restrict__ Bt,
                                                   void* __restrict__ Cout,
                                                   const float* __restrict__ bias,
                                                   const float* __restrict__ res,
                                                   int M, int Nn, int K, int gx) {
    int tid  = threadIdx.x;
    int lane = tid & 63, wave = tid >> 6;
    int wm = wave >> 1, wn = wave & 1;

    int nwg = gridDim.x, lin = blockIdx.x;
    int swz = (lin & 7) * (nwg >> 3) + (lin >> 3);
    int by = swz / gx, bx = swz - by * gx;
    int m0 = by * 128, n0 = bx * 128;

    int qr = lane & 15, grp = lane >> 4;
    const ushort* Ab = A  + (size_t)(m0 + wm * 64 + qr) * K + grp * 8;
    const ushort* Bb = Bt + (size_t)(n0 + wn * 64 + qr) * K + grp * 8;
    const size_t mstr = (size_t)16 * K;   // 16-row block stride (elements)

    floatx4 acc[4][4] = {};
    int nt = K >> 6;                      // even for all call sites

    short8 aE[2][4], bE[2][4], aO[2][4], bO[2][4];

#define LOADSET(as, bs, t_)                                                    \
    {                                                                          \
        _Pragma("unroll") for (int ks = 0; ks < 2; ks++) {                     \
            _Pragma("unroll") for (int mi = 0; mi < 4; mi++)                   \
                as[ks][mi] = *(const short8*)(Ab + mi * mstr + (size_t)(t_) * 64 + ks * 32); \
            _Pragma("unroll") for (int ni = 0; ni < 4; ni++)                   \
                bs[ks][ni] = *(const short8*)(Bb + ni * mstr + (size_t)(t_) * 64 + ks * 32); \
        }                                                                      \
    }
#define MFMASET(as, bs)                                                        \
    {                                                                          \
        _Pragma("unroll") for (int ks = 0; ks < 2; ks++)                       \
            _Pragma("unroll") for (int mi = 0; mi < 4; mi++)                   \
                _Pragma("unroll") for (int ni = 0; ni < 4; ni++)               \
                    acc[mi][ni] = MFMA32(as[ks][mi], bs[ks][ni], acc[mi][ni]); \
    }

    LOADSET(aE, bE, 0);
    for (int t = 0; t < nt; t += 2) {
        LOADSET(aO, bO, t + 1);           // nt even -> t+1 < nt always
        MFMASET(aE, bE);
        if (t + 2 < nt) LOADSET(aE, bE, t + 2);
        MFMASET(aO, bO);
    }
#undef LOADSET
#undef MFMASET

    // Epilogue: C/D layout col=lane&15, row=(lane>>4)*4+reg
    int r0 = m0 + wm * 64 + grp * 4;
    int c0 = n0 + wn * 64 + qr;
#pragma unroll
    for (int mi = 0; mi < 4; mi++) {
#pragma unroll
        for (int ni = 0; ni < 4; ni++) {
            int col = c0 + ni * 16;
            if (MASKN && col >= Nn) continue;
#pragma unroll
            for (int r = 0; r < 4; r++) {
                int row = r0 + mi * 16 + r;
                size_t idx = (size_t)row * Nn + col;
                float v = acc[mi][ni][r];
                if constexpr (EPI == 0) {
                    ((float*)Cout)[idx] = v;
                } else if constexpr (EPI == 1) {
                    ((float*)Cout)[idx] = v + bias[col] + res[idx];
                } else {
                    ((ushort*)Cout)[idx] = f2b(gelu_f(v + bias[col]));
                }
            }
        }
    }
}

// ---------------------------------------------------------------------------
// MFMA attention. Block = (bh, 128-q group); 512 blocks, 256 thr (4 waves),
// each wave owns 2 q-tiles of 16. K staged bf16 [1024][12], V^T bf16
// [12][1032]. S^T = mfma16(K,Q); P^T C-layout == B-frag layout -> PV direct.
// Output: ao bf16 [8192][128] (cols 96..127 pre-zeroed).
// ---------------------------------------------------------------------------
__global__ __launch_bounds__(256) void attn_mfma_kernel(const float* __restrict__ qkv,
                                                        ushort* __restrict__ ao) {
    __shared__ ushort Kt[NSEQ * 12];     // [j][d]
    __shared__ ushort VT[12 * 1032];     // [d][j], stride 1032
    int bh = blockIdx.x >> 3, qg = blockIdx.x & 7;
    int b = bh >> 3, h = bh & 7;
    int tid = threadIdx.x;
    const float* base = qkv + (size_t)b * NSEQ * (3 * INNER);

#pragma unroll
    for (int i = 0; i < 4; i++) {
        int j = i * 256 + tid;
        const float* kp = base + (size_t)j * (3 * INNER) + INNER + h * HEAD_D;
        float4 a0 = *(const float4*)(kp);
        float4 a1 = *(const float4*)(kp + 4);
        float4 a2 = *(const float4*)(kp + 8);
        uint2* kw = (uint2*)(&Kt[j * 12]);
        kw[0] = make_uint2(pk2(a0.x, a0.y), pk2(a0.z, a0.w));
        kw[1] = make_uint2(pk2(a1.x, a1.y), pk2(a1.z, a1.w));
        kw[2] = make_uint2(pk2(a2.x, a2.y), pk2(a2.z, a2.w));
        const float* vp = kp + INNER;
        float4 v0 = *(const float4*)(vp);
        float4 v1 = *(const float4*)(vp + 4);
        float4 v2 = *(const float4*)(vp + 8);
        VT[0 * 1032 + j] = f2b(v0.x);  VT[1 * 1032 + j]  = f2b(v0.y);
        VT[2 * 1032 + j] = f2b(v0.z);  VT[3 * 1032 + j]  = f2b(v0.w);
        VT[4 * 1032 + j] = f2b(v1.x);  VT[5 * 1032 + j]  = f2b(v1.y);
        VT[6 * 1032 + j] = f2b(v1.z);  VT[7 * 1032 + j]  = f2b(v1.w);
        VT[8 * 1032 + j] = f2b(v2.x);  VT[9 * 1032 + j]  = f2b(v2.y);
        VT[10 * 1032 + j] = f2b(v2.z); VT[11 * 1032 + j] = f2b(v2.w);
    }
    __syncthreads();

    int lane = tid & 63, wave = tid >> 6;
    int qrow = lane & 15, grp = lane >> 4;
    const float scale = 0.102062072615966f;  // 96^-0.5

    s4b qf[2];
#pragma unroll
    for (int t = 0; t < 2; t++) {
        qf[t] = (s4b)0;
        if (grp < 3) {
            int q = qg * 128 + (wave * 2 + t) * 16 + qrow;
            const float* qp = base + (size_t)q * (3 * INNER) + h * HEAD_D + grp * 4;
            float4 qv = *(const float4*)(qp);
            uint2 u = make_uint2(pk2(qv.x * scale, qv.y * scale),
                                 pk2(qv.z * scale, qv.w * scale));
            qf[t] = __builtin_bit_cast(s4b, u);
        }
    }

    floatx4 acc[2] = {};
    float l[2] = {0.f, 0.f};
    int kc = (grp < 3) ? grp : 0;
    int dv = (qrow < 12) ? qrow : 0;
    bool kz = (grp == 3), vz = (qrow >= 12);
    const floatx4 z4 = {};

    for (int jt = 0; jt < 64; jt++) {
        s4b kf = *(const s4b*)(&Kt[(jt * 16 + qrow) * 12 + kc * 4]);
        if (kz) kf = (s4b)0;
        s4b vf = *(const s4b*)(&VT[dv * 1032 + jt * 16 + grp * 4]);
        if (vz) vf = (s4b)0;
#pragma unroll
        for (int t = 0; t < 2; t++) {
            floatx4 st = mfma16(kf, qf[t], z4);
            float p0 = __expf(st[0]), p1 = __expf(st[1]);
            float p2 = __expf(st[2]), p3 = __expf(st[3]);
            l[t] += (p0 + p1) + (p2 + p3);
            uint2 u = make_uint2(pk2(p0, p1), pk2(p2, p3));
            acc[t] = mfma16(vf, __builtin_bit_cast(s4b, u), acc[t]);
        }
    }

#pragma unroll
    for (int t = 0; t < 2; t++) {
        float lt = l[t];
        lt += __shfl_xor(lt, 16);
        lt += __shfl_xor(lt, 32);
        float inv = 1.f / lt;
        if (grp < 3) {
            int q = qg * 128 + (wave * 2 + t) * 16 + qrow;
            ushort4 o;
            o.x = f2b(acc[t][0] * inv);
            o.y = f2b(acc[t][1] * inv);
            o.z = f2b(acc[t][2] * inv);
            o.w = f2b(acc[t][3] * inv);
            *reinterpret_cast<ushort4*>(&ao[(size_t)(b * NSEQ + q) * 128 + h * HEAD_D + grp * 4]) = o;
        }
    }
}

// ---------------------------------------------------------------------------
// Launch
// ---------------------------------------------------------------------------
extern "C" void kernel_launch(void* const* d_in, const int* in_sizes, int n_in,
                              void* d_out, int out_size, void* d_ws, size_t ws_size,
                              hipStream_t stream) {
    const float* inputs = (const float*)d_in[0];
    const float* ln1_g  = (const float*)d_in[3];
    const float* ln1_b  = (const float*)d_in[4];
    const float* w_qkv  = (const float*)d_in[5];
    const float* w_proj = (const float*)d_in[6];
    const float* b_proj = (const float*)d_in[7];
    const float* ln2_g  = (const float*)d_in[8];
    const float* ln2_b  = (const float*)d_in[9];
    const float* w1     = (const float*)d_in[10];
    const float* b1     = (const float*)d_in[11];
    const float* w2     = (const float*)d_in[12];
    const float* b2     = (const float*)d_in[13];
    float* out = (float*)d_out;

    // Workspace layout (bytes):
    //  h_bf    : 8192*768*2   = 12,582,912  @ 0
    //  qkv     : 8192*288*4   =  9,437,184  @ 12,582,912
    //  ao_pad  : 8192*128*2   =  2,097,152  @ 22,020,096  (bf16, K-padded)
    //  wproj_t : 768*128*2    =    196,608  @ 24,117,248
    //  x1      : 8192*768*4   = 25,165,824  @ 25,165,824
    //  m2      : 8192*3072*2  = 50,331,648  @ 50,331,648
    //  wqkv_t  : 384*768*2    =    589,824  @ 100,663,296
    //  w1_t    : 3072*768*2   =  4,718,592  @ 101,253,120
    //  w2_t    : 768*3072*2   =  4,718,592  @ 105,971,712
    char* ws = (char*)d_ws;
    ushort* h_bf    = (ushort*)(ws);
    float*  qkv     = (float*)(ws + 12582912);
    ushort* ao_pad  = (ushort*)(ws + 22020096);
    ushort* wproj_t = (ushort*)(ws + 24117248);
    float*  x1      = (float*)(ws + 25165824);
    ushort* m2      = (ushort*)(ws + 50331648);
    ushort* wqkv_t  = (ushort*)(ws + 100663296);
    ushort* w1_t    = (ushort*)(ws + 101253120);
    ushort* w2_t    = (ushort*)(ws + 105971712);

    dim3 tb(32, 8);
    convt_kernel<<<dim3(12, 24), tb, 0, stream>>>(w_qkv, wqkv_t, EMB, 3 * INNER, 384);
    convt_kernel<<<dim3(96, 24), tb, 0, stream>>>(w1, w1_t, EMB, MLP_DIM, MLP_DIM);
    convt_kernel<<<dim3(24, 96), tb, 0, stream>>>(w2, w2_t, MLP_DIM, EMB, EMB);
    convt_pad_kernel<<<dim3(24, 4), tb, 0, stream>>>(w_proj, wproj_t, INNER, EMB, 128);

    // 1) LN1 -> bf16
    ln_bf16_kernel<<<ROWS / 4, 256, 0, stream>>>(inputs, ln1_g, ln1_b, h_bf);
    // 2) qkv = h @ w_qkv   [8192,288] K=768 (Npad=384); grid 3x64=192
    gemm_stream<0, true><<<3 * (ROWS / 128), 256, 0, stream>>>(
        h_bf, wqkv_t, qkv, nullptr, nullptr, ROWS, 3 * INNER, EMB, 3);
    // 3) attention -> ao_pad bf16 [8192,128]
    hipMemsetAsync(ao_pad, 0, (size_t)ROWS * 128 * 2, stream);
    attn_mfma_kernel<<<512, 256, 0, stream>>>(qkv, ao_pad);
    // 4) x1 = inputs + ao @ w_proj + b_proj   [8192,768] K=128(pad); grid 6x64
    gemm_stream<1, false><<<6 * (ROWS / 128), 256, 0, stream>>>(
        ao_pad, wproj_t, x1, b_proj, inputs, ROWS, EMB, 128, 6);
    // 5) LN2 -> bf16
    ln_bf16_kernel<<<ROWS / 4, 256, 0, stream>>>(x1, ln2_g, ln2_b, h_bf);
    // 6) m2 = gelu(h @ w1 + b1) -> bf16   [8192,3072] K=768; grid 24x64=1536
    gemm_stream<2, false><<<24 * (ROWS / 128), 256, 0, stream>>>(
        h_bf, w1_t, m2, b1, nullptr, ROWS, MLP_DIM, EMB, 24);
    // 7) out = x1 + m2 @ w2 + b2   [8192,768] K=3072; grid 6x64=384
    gemm_stream<1, false><<<6 * (ROWS / 128), 256, 0, stream>>>(
        m2, w2_t, out, b2, x1, ROWS, EMB, MLP_DIM, 6);
}

// Round 11
// 192.496 us; speedup vs baseline: 2.4449x; 2.4449x over previous
//
#include <hip/hip_runtime.h>
#include <hip/hip_bf16.h>
#include <math.h>

// Problem constants
#define BB 8
#define NSEQ 1024
#define EMB 768
#define HEADS 8
#define INNER 96
#define HEAD_D 12
#define MLP_DIM 3072
#define ROWS (BB * NSEQ)   // 8192

using short8  = __attribute__((ext_vector_type(8))) short;
using s4b     = __attribute__((ext_vector_type(4))) short;
using floatx4 = __attribute__((ext_vector_type(4))) float;

// global -> LDS async copy, 16 B per lane. LDS dest must be wave-uniform base;
// HW adds lane*16. Global source is per-lane.
#define GLL16(g, l)                                                          \
    __builtin_amdgcn_global_load_lds(                                        \
        (const __attribute__((address_space(1))) void*)(g),                  \
        (__attribute__((address_space(3))) void*)(l), 16, 0, 0)

static __device__ __forceinline__ ushort f2b(float x) {
    __hip_bfloat16 h = __float2bfloat16(x);
    return *reinterpret_cast<ushort*>(&h);
}
static __device__ __forceinline__ uint pk2(float a, float b) {
    return (uint)f2b(a) | ((uint)f2b(b) << 16);
}

// 16x16x16 bf16 MFMA (a,b: 4 bf16 = 2 VGPR; c/d: 4 f32)
static __device__ __forceinline__ floatx4 mfma16(s4b a, s4b b, floatx4 c) {
#if __has_builtin(__builtin_amdgcn_mfma_f32_16x16x16_bf16)
    return __builtin_amdgcn_mfma_f32_16x16x16_bf16(a, b, c, 0, 0, 0);
#elif __has_builtin(__builtin_amdgcn_mfma_f32_16x16x16bf16_1k)
    return __builtin_amdgcn_mfma_f32_16x16x16bf16_1k(a, b, c, 0, 0, 0);
#else
    floatx4 d;
    asm("v_mfma_f32_16x16x16_bf16 %0, %1, %2, %3" : "=v"(d) : "v"(a), "v"(b), "v"(c));
    return d;
#endif
}
#define MFMA32(a, b, c) __builtin_amdgcn_mfma_f32_16x16x32_bf16((a), (b), (c), 0, 0, 0)

// ---------------------------------------------------------------------------
// LayerNorm: one wave per row of 768, bf16 output. 4 rows / 256-thr block.
// ---------------------------------------------------------------------------
__global__ __launch_bounds__(256) void ln_bf16_kernel(const float* __restrict__ x,
                                                      const float* __restrict__ g,
                                                      const float* __restrict__ b,
                                                      ushort* __restrict__ out) {
    int row  = blockIdx.x * 4 + (threadIdx.x >> 6);
    int lane = threadIdx.x & 63;
    const float* xr = x + (size_t)row * EMB;
    float v[12];
    float s = 0.f;
#pragma unroll
    for (int i = 0; i < 12; i++) {
        v[i] = xr[lane + i * 64];
        s += v[i];
    }
#pragma unroll
    for (int off = 32; off; off >>= 1) s += __shfl_xor(s, off);
    float mu = s * (1.0f / EMB);
    float ss = 0.f;
#pragma unroll
    for (int i = 0; i < 12; i++) { float d = v[i] - mu; ss += d * d; }
#pragma unroll
    for (int off = 32; off; off >>= 1) ss += __shfl_xor(ss, off);
    float rstd = rsqrtf(ss * (1.0f / EMB) + 1e-5f);
    ushort* orow = out + (size_t)row * EMB;
#pragma unroll
    for (int i = 0; i < 12; i++) {
        int c = lane + i * 64;
        orow[c] = f2b((v[i] - mu) * rstd * g[c] + b[c]);
    }
}

// ---------------------------------------------------------------------------
// Weight convert+transpose: out[n][k] = bf16(in[k][n]); n in [0,Npad),
// zeros for n >= N. 32x32 tiles via LDS.
// ---------------------------------------------------------------------------
__global__ __launch_bounds__(256) void convt_kernel(const float* __restrict__ in,
                                                    ushort* __restrict__ out,
                                                    int K, int N, int Npad) {
    __shared__ float t[32][33];
    int n0 = blockIdx.x * 32, k0 = blockIdx.y * 32;
    int tx = threadIdx.x, ty = threadIdx.y;
#pragma unroll
    for (int i = 0; i < 32; i += 8) {
        int n = n0 + tx;
        t[ty + i][tx] = (n < N) ? in[(size_t)(k0 + ty + i) * N + n] : 0.f;
    }
    __syncthreads();
#pragma unroll
    for (int i = 0; i < 32; i += 8) {
        out[(size_t)(n0 + ty + i) * K + k0 + tx] = f2b(t[tx][ty + i]);
    }
}

// Variant padding K: out[n][k] for k in [0,Kpad), zero for k >= K.
__global__ __launch_bounds__(256) void convt_pad_kernel(const float* __restrict__ in,
                                                        ushort* __restrict__ out,
                                                        int K, int N, int Kpad) {
    __shared__ float t[32][33];
    int n0 = blockIdx.x * 32, k0 = blockIdx.y * 32;
    int tx = threadIdx.x, ty = threadIdx.y;
#pragma unroll
    for (int i = 0; i < 32; i += 8) {
        int k = k0 + ty + i;
        t[ty + i][tx] = (k < K) ? in[(size_t)k * N + n0 + tx] : 0.f;
    }
    __syncthreads();
#pragma unroll
    for (int i = 0; i < 32; i += 8) {
        out[(size_t)(n0 + ty + i) * Kpad + k0 + tx] = f2b(t[tx][ty + i]);
    }
}

// ---------------------------------------------------------------------------
// bf16 MFMA GEMM: C[M,Nn] = A[M,K](bf16) @ Bt[Npad,K](bf16)^T  (+ epilogue)
// 128x128 tile, BK=64, 4 waves (2x2), 4x4 16x16x32 fragments per wave.
// Double-buffered LDS (64 KB -> 2 blocks/CU) + counted-vmcnt pipeline:
//   iter t:   ds_read all frags(buf[cur]); lgkmcnt(0); barrier;   <- buf dead
//             STAGE(t+2 -> buf[cur]);  vmcnt(8) [t+1 landed];
//             32 MFMA;  barrier;  cur^=1
// Race-free: a region is only re-staged after the barrier following its last
// read; tile t+1 readiness = own-wave vmcnt(8) + barrier.
// 1-D grid with bijective XCD-chunked swizzle (T1). gridDim.x % 8 == 0.
// ---------------------------------------------------------------------------
template <int EPI, bool MASKN>
__global__ __launch_bounds__(256) void gemm_mfma(const ushort* __restrict__ A,
                                                 const ushort* __restrict__ Bt,
                                                 void* __restrict__ Cout,
                                                 const float* __restrict__ bias,
                                                 const float* __restrict__ res,
                                                 int M, int Nn, int K, int gx) {
    __shared__ ushort As[2][128 * 64];  // [row][k] swizzled: chunk c at slot c^(row&7)
    __shared__ ushort Bs[2][128 * 64];
    int tid  = threadIdx.x;
    int lane = tid & 63, wave = tid >> 6;
    int wm = wave >> 1, wn = wave & 1;

    // XCD-chunked bijective swizzle: HW assigns block i -> XCD i%8.
    int nwg = gridDim.x;
    int lin = blockIdx.x;
    int swz = (lin & 7) * (nwg >> 3) + (lin >> 3);
    int by = swz / gx, bx = swz - by * gx;
    int m0 = by * 128, n0 = bx * 128;

    floatx4 acc[4][4] = {};

    int srow = lane >> 3;
    int slot = lane & 7;
    int nt = K >> 6;

    // stage one 64-k tile (A half + B half) into buffer bufi: 8 GLL16/thread
    auto STAGE = [&](int t, int bufi) {
        int k0 = t << 6;
#pragma unroll
        for (int r = 0; r < 4; r++) {
            int row = r * 32 + wave * 8 + srow;
            int c   = slot ^ (row & 7);
            const ushort* ga = A  + (size_t)(m0 + row) * K + k0 + c * 8;
            const ushort* gb = Bt + (size_t)(n0 + row) * K + k0 + c * 8;
            GLL16(ga, (char*)&As[bufi][0] + r * 4096 + wave * 1024);
            GLL16(gb, (char*)&Bs[bufi][0] + r * 4096 + wave * 1024);
        }
    };

    // Prologue: fill both buffers, wait for tile 0 only (counted).
    STAGE(0, 0);
    STAGE(1, 1);
    asm volatile("s_waitcnt vmcnt(8)" ::: "memory");
    __builtin_amdgcn_sched_barrier(0);
    __builtin_amdgcn_s_barrier();

    int cur = 0;
    for (int t = 0; t < nt; ++t) {
        // 1. read ALL fragments of tile t into registers
        short8 af[2][4], bfr[2][4];
#pragma unroll
        for (int ks = 0; ks < 2; ks++) {
#pragma unroll
            for (int mi = 0; mi < 4; mi++) {
                int row = wm * 64 + mi * 16 + (lane & 15);
                int c   = ks * 4 + (lane >> 4);
                af[ks][mi] = *(const short8*)(&As[cur][0] + row * 64 + (c ^ (row & 7)) * 8);
            }
#pragma unroll
            for (int ni = 0; ni < 4; ni++) {
                int col = wn * 64 + ni * 16 + (lane & 15);
                int c   = ks * 4 + (lane >> 4);
                bfr[ks][ni] = *(const short8*)(&Bs[cur][0] + col * 64 + (c ^ (col & 7)) * 8);
            }
        }
        asm volatile("s_waitcnt lgkmcnt(0)" ::: "memory");
        __builtin_amdgcn_s_barrier();           // buf[cur] now dead for all waves
        __builtin_amdgcn_sched_barrier(0);

        // 3. stage tile t+2 into the dead buffer (clamped; tail re-load is benign)
        int tn = t + 2; if (tn > nt - 1) tn = nt - 1;
        STAGE(tn, cur);

        // 4. counted wait: tile t+1's 8 loads landed; ours stay in flight
        asm volatile("s_waitcnt vmcnt(8)" ::: "memory");
        __builtin_amdgcn_sched_barrier(0);

        // 5. MFMA
#pragma unroll
        for (int ks = 0; ks < 2; ks++)
#pragma unroll
            for (int mi = 0; mi < 4; mi++)
#pragma unroll
                for (int ni = 0; ni < 4; ni++)
                    acc[mi][ni] = MFMA32(af[ks][mi], bfr[ks][ni], acc[mi][ni]);

        __builtin_amdgcn_s_barrier();           // all waves' vmcnt(8) passed
        __builtin_amdgcn_sched_barrier(0);
        cur ^= 1;
    }

    int r0 = m0 + wm * 64 + (lane >> 4) * 4;
    int c0 = n0 + wn * 64 + (lane & 15);
#pragma unroll
    for (int mi = 0; mi < 4; mi++) {
#pragma unroll
        for (int ni = 0; ni < 4; ni++) {
            int col = c0 + ni * 16;
            if (MASKN && col >= Nn) continue;
#pragma unroll
            for (int r = 0; r < 4; r++) {
                int row = r0 + mi * 16 + r;
                size_t idx = (size_t)row * Nn + col;
                float v = acc[mi][ni][r];
                if constexpr (EPI == 0) {
                    ((float*)Cout)[idx] = v;
                } else if constexpr (EPI == 1) {
                    ((float*)Cout)[idx] = v + bias[col] + res[idx];
                } else {
                    v += bias[col];
                    // tanh-GELU via sigmoid; |err| ~3e-4 << bf16 rounding of m2.
                    float u = v * (1.0f + 0.044715f * v * v);
                    float gl = v / (1.0f + __expf(-1.5957691216057308f * u));
                    ((ushort*)Cout)[idx] = f2b(gl);
                }
            }
        }
    }
}

// ---------------------------------------------------------------------------
// MFMA attention. Block = (bh, 128-q group); 512 blocks, 256 thr (4 waves),
// each wave owns 2 q-tiles of 16. K staged bf16 [1024][12], V^T bf16
// [12][1032]. S^T = mfma16(K,Q); P^T C-layout == B-frag layout -> PV direct.
// Output: ao bf16 [8192][128] (cols 96..127 pre-zeroed).
// ---------------------------------------------------------------------------
__global__ __launch_bounds__(256) void attn_mfma_kernel(const float* __restrict__ qkv,
                                                        ushort* __restrict__ ao) {
    __shared__ ushort Kt[NSEQ * 12];     // [j][d]
    __shared__ ushort VT[12 * 1032];     // [d][j], stride 1032
    int bh = blockIdx.x >> 3, qg = blockIdx.x & 7;
    int b = bh >> 3, h = bh & 7;
    int tid = threadIdx.x;
    const float* base = qkv + (size_t)b * NSEQ * (3 * INNER);

#pragma unroll
    for (int i = 0; i < 4; i++) {
        int j = i * 256 + tid;
        const float* kp = base + (size_t)j * (3 * INNER) + INNER + h * HEAD_D;
        float4 a0 = *(const float4*)(kp);
        float4 a1 = *(const float4*)(kp + 4);
        float4 a2 = *(const float4*)(kp + 8);
        uint2* kw = (uint2*)(&Kt[j * 12]);
        kw[0] = make_uint2(pk2(a0.x, a0.y), pk2(a0.z, a0.w));
        kw[1] = make_uint2(pk2(a1.x, a1.y), pk2(a1.z, a1.w));
        kw[2] = make_uint2(pk2(a2.x, a2.y), pk2(a2.z, a2.w));
        const float* vp = kp + INNER;
        float4 v0 = *(const float4*)(vp);
        float4 v1 = *(const float4*)(vp + 4);
        float4 v2 = *(const float4*)(vp + 8);
        VT[0 * 1032 + j] = f2b(v0.x);  VT[1 * 1032 + j]  = f2b(v0.y);
        VT[2 * 1032 + j] = f2b(v0.z);  VT[3 * 1032 + j]  = f2b(v0.w);
        VT[4 * 1032 + j] = f2b(v1.x);  VT[5 * 1032 + j]  = f2b(v1.y);
        VT[6 * 1032 + j] = f2b(v1.z);  VT[7 * 1032 + j]  = f2b(v1.w);
        VT[8 * 1032 + j] = f2b(v2.x);  VT[9 * 1032 + j]  = f2b(v2.y);
        VT[10 * 1032 + j] = f2b(v2.z); VT[11 * 1032 + j] = f2b(v2.w);
    }
    __syncthreads();

    int lane = tid & 63, wave = tid >> 6;
    int qrow = lane & 15, grp = lane >> 4;
    const float scale = 0.102062072615966f;  // 96^-0.5

    s4b qf[2];
#pragma unroll
    for (int t = 0; t < 2; t++) {
        qf[t] = (s4b)0;
        if (grp < 3) {
            int q = qg * 128 + (wave * 2 + t) * 16 + qrow;
            const float* qp = base + (size_t)q * (3 * INNER) + h * HEAD_D + grp * 4;
            float4 qv = *(const float4*)(qp);
            uint2 u = make_uint2(pk2(qv.x * scale, qv.y * scale),
                                 pk2(qv.z * scale, qv.w * scale));
            qf[t] = __builtin_bit_cast(s4b, u);
        }
    }

    floatx4 acc[2] = {};
    float l[2] = {0.f, 0.f};
    int kc = (grp < 3) ? grp : 0;
    int dv = (qrow < 12) ? qrow : 0;
    bool kz = (grp == 3), vz = (qrow >= 12);
    const floatx4 z4 = {};

    for (int jt = 0; jt < 64; jt++) {
        s4b kf = *(const s4b*)(&Kt[(jt * 16 + qrow) * 12 + kc * 4]);
        if (kz) kf = (s4b)0;
        s4b vf = *(const s4b*)(&VT[dv * 1032 + jt * 16 + grp * 4]);
        if (vz) vf = (s4b)0;
#pragma unroll
        for (int t = 0; t < 2; t++) {
            floatx4 st = mfma16(kf, qf[t], z4);
            float p0 = __expf(st[0]), p1 = __expf(st[1]);
            float p2 = __expf(st[2]), p3 = __expf(st[3]);
            l[t] += (p0 + p1) + (p2 + p3);
            uint2 u = make_uint2(pk2(p0, p1), pk2(p2, p3));
            acc[t] = mfma16(vf, __builtin_bit_cast(s4b, u), acc[t]);
        }
    }

#pragma unroll
    for (int t = 0; t < 2; t++) {
        float lt = l[t];
        lt += __shfl_xor(lt, 16);
        lt += __shfl_xor(lt, 32);
        float inv = 1.f / lt;
        if (grp < 3) {
            int q = qg * 128 + (wave * 2 + t) * 16 + qrow;
            ushort4 o;
            o.x = f2b(acc[t][0] * inv);
            o.y = f2b(acc[t][1] * inv);
            o.z = f2b(acc[t][2] * inv);
            o.w = f2b(acc[t][3] * inv);
            *reinterpret_cast<ushort4*>(&ao[(size_t)(b * NSEQ + q) * 128 + h * HEAD_D + grp * 4]) = o;
        }
    }
}

// ---------------------------------------------------------------------------
// Launch
// ---------------------------------------------------------------------------
extern "C" void kernel_launch(void* const* d_in, const int* in_sizes, int n_in,
                              void* d_out, int out_size, void* d_ws, size_t ws_size,
                              hipStream_t stream) {
    const float* inputs = (const float*)d_in[0];
    const float* ln1_g  = (const float*)d_in[3];
    const float* ln1_b  = (const float*)d_in[4];
    const float* w_qkv  = (const float*)d_in[5];
    const float* w_proj = (const float*)d_in[6];
    const float* b_proj = (const float*)d_in[7];
    const float* ln2_g  = (const float*)d_in[8];
    const float* ln2_b  = (const float*)d_in[9];
    const float* w1     = (const float*)d_in[10];
    const float* b1     = (const float*)d_in[11];
    const float* w2     = (const float*)d_in[12];
    const float* b2     = (const float*)d_in[13];
    float* out = (float*)d_out;

    // Workspace layout (bytes):
    //  h_bf    : 8192*768*2   = 12,582,912  @ 0
    //  qkv     : 8192*288*4   =  9,437,184  @ 12,582,912
    //  ao_pad  : 8192*128*2   =  2,097,152  @ 22,020,096  (bf16, K-padded)
    //  wproj_t : 768*128*2    =    196,608  @ 24,117,248
    //  x1      : 8192*768*4   = 25,165,824  @ 25,165,824
    //  m2      : 8192*3072*2  = 50,331,648  @ 50,331,648
    //  wqkv_t  : 384*768*2    =    589,824  @ 100,663,296
    //  w1_t    : 3072*768*2   =  4,718,592  @ 101,253,120
    //  w2_t    : 768*3072*2   =  4,718,592  @ 105,971,712
    char* ws = (char*)d_ws;
    ushort* h_bf    = (ushort*)(ws);
    float*  qkv     = (float*)(ws + 12582912);
    ushort* ao_pad  = (ushort*)(ws + 22020096);
    ushort* wproj_t = (ushort*)(ws + 24117248);
    float*  x1      = (float*)(ws + 25165824);
    ushort* m2      = (ushort*)(ws + 50331648);
    ushort* wqkv_t  = (ushort*)(ws + 100663296);
    ushort* w1_t    = (ushort*)(ws + 101253120);
    ushort* w2_t    = (ushort*)(ws + 105971712);

    dim3 tb(32, 8);
    convt_kernel<<<dim3(12, 24), tb, 0, stream>>>(w_qkv, wqkv_t, EMB, 3 * INNER, 384);
    convt_kernel<<<dim3(96, 24), tb, 0, stream>>>(w1, w1_t, EMB, MLP_DIM, MLP_DIM);
    convt_kernel<<<dim3(24, 96), tb, 0, stream>>>(w2, w2_t, MLP_DIM, EMB, EMB);
    convt_pad_kernel<<<dim3(24, 4), tb, 0, stream>>>(w_proj, wproj_t, INNER, EMB, 128);

    // 1) LN1 -> bf16
    ln_bf16_kernel<<<ROWS / 4, 256, 0, stream>>>(inputs, ln1_g, ln1_b, h_bf);
    // 2) qkv = h @ w_qkv   [8192,288] K=768 (Npad=384); grid 3x64=192 (%8==0)
    gemm_mfma<0, true><<<3 * (ROWS / 128), 256, 0, stream>>>(
        h_bf, wqkv_t, qkv, nullptr, nullptr, ROWS, 3 * INNER, EMB, 3);
    // 3) attention -> ao_pad bf16 [8192,128]
    hipMemsetAsync(ao_pad, 0, (size_t)ROWS * 128 * 2, stream);
    attn_mfma_kernel<<<512, 256, 0, stream>>>(qkv, ao_pad);
    // 4) x1 = inputs + ao @ w_proj + b_proj   [8192,768] K=128(pad); grid 6x64
    gemm_mfma<1, false><<<6 * (ROWS / 128), 256, 0, stream>>>(
        ao_pad, wproj_t, x1, b_proj, inputs, ROWS, EMB, 128, 6);
    // 5) LN2 -> bf16
    ln_bf16_kernel<<<ROWS / 4, 256, 0, stream>>>(x1, ln2_g, ln2_b, h_bf);
    // 6) m2 = gelu(h @ w1 + b1) -> bf16   [8192,3072] K=768; grid 24x64=1536
    gemm_mfma<2, false><<<24 * (ROWS / 128), 256, 0, stream>>>(
        h_bf, w1_t, m2, b1, nullptr, ROWS, MLP_DIM, EMB, 24);
    // 7) out = x1 + m2 @ w2 + b2   [8192,768] K=3072; grid 6x64=384
    gemm_mfma<1, false><<<6 * (ROWS / 128), 256, 0, stream>>>(
        m2, w2_t, out, b2, x1, ROWS, EMB, MLP_DIM, 6);
}

// Round 12
// 186.072 us; speedup vs baseline: 2.5293x; 1.0345x over previous
//
#include <hip/hip_runtime.h>
#include <hip/hip_bf16.h>
#include <math.h>

// Problem constants
#define BB 8
#define NSEQ 1024
#define EMB 768
#define HEADS 8
#define INNER 96
#define HEAD_D 12
#define MLP_DIM 3072
#define ROWS (BB * NSEQ)   // 8192

using short8  = __attribute__((ext_vector_type(8))) short;
using s4b     = __attribute__((ext_vector_type(4))) short;
using floatx4 = __attribute__((ext_vector_type(4))) float;

// global -> LDS async copy, 16 B per lane. LDS dest must be wave-uniform base;
// HW adds lane*16. Global source is per-lane.
#define GLL16(g, l)                                                          \
    __builtin_amdgcn_global_load_lds(                                        \
        (const __attribute__((address_space(1))) void*)(g),                  \
        (__attribute__((address_space(3))) void*)(l), 16, 0, 0)

static __device__ __forceinline__ ushort f2b(float x) {
    __hip_bfloat16 h = __float2bfloat16(x);
    return *reinterpret_cast<ushort*>(&h);
}
static __device__ __forceinline__ float b2f(ushort u) {
    return __uint_as_float(((uint)u) << 16);
}
static __device__ __forceinline__ uint pk2(float a, float b) {
    return (uint)f2b(a) | ((uint)f2b(b) << 16);
}

// 16x16x16 bf16 MFMA (a,b: 4 bf16 = 2 VGPR; c/d: 4 f32)
static __device__ __forceinline__ floatx4 mfma16(s4b a, s4b b, floatx4 c) {
#if __has_builtin(__builtin_amdgcn_mfma_f32_16x16x16_bf16)
    return __builtin_amdgcn_mfma_f32_16x16x16_bf16(a, b, c, 0, 0, 0);
#elif __has_builtin(__builtin_amdgcn_mfma_f32_16x16x16bf16_1k)
    return __builtin_amdgcn_mfma_f32_16x16x16bf16_1k(a, b, c, 0, 0, 0);
#else
    floatx4 d;
    asm("v_mfma_f32_16x16x16_bf16 %0, %1, %2, %3" : "=v"(d) : "v"(a), "v"(b), "v"(c));
    return d;
#endif
}
#define MFMA32(a, b, c) __builtin_amdgcn_mfma_f32_16x16x32_bf16((a), (b), (c), 0, 0, 0)

static __device__ __forceinline__ float gelu_f(float v) {
    // tanh-GELU via sigmoid; |err| ~3e-4 << bf16 rounding.
    float u = v * (1.0f + 0.044715f * v * v);
    return v / (1.0f + __expf(-1.5957691216057308f * u));
}

// ---------------------------------------------------------------------------
// LayerNorm, fp32 input -> bf16 out. One wave per row of 768; vectorized
// float4 loads (16B/lane) + ushort4 stores (8B/lane). 4 rows / block.
// ---------------------------------------------------------------------------
__global__ __launch_bounds__(256) void ln_f32in_kernel(const float* __restrict__ x,
                                                       const float* __restrict__ g,
                                                       const float* __restrict__ b,
                                                       ushort* __restrict__ out) {
    int row  = blockIdx.x * 4 + (threadIdx.x >> 6);
    int lane = threadIdx.x & 63;
    const float* xr = x + (size_t)row * EMB;
    float4 vv[3];
#pragma unroll
    for (int i = 0; i < 3; i++)
        vv[i] = *reinterpret_cast<const float4*>(xr + i * 256 + lane * 4);
    float s = 0.f;
#pragma unroll
    for (int i = 0; i < 3; i++) s += (vv[i].x + vv[i].y) + (vv[i].z + vv[i].w);
#pragma unroll
    for (int off = 32; off; off >>= 1) s += __shfl_xor(s, off);
    float mu = s * (1.0f / EMB);
    float ss = 0.f;
#pragma unroll
    for (int i = 0; i < 3; i++) {
        float d0 = vv[i].x - mu, d1 = vv[i].y - mu, d2 = vv[i].z - mu, d3 = vv[i].w - mu;
        ss += (d0 * d0 + d1 * d1) + (d2 * d2 + d3 * d3);
    }
#pragma unroll
    for (int off = 32; off; off >>= 1) ss += __shfl_xor(ss, off);
    float rstd = rsqrtf(ss * (1.0f / EMB) + 1e-5f);
    ushort* orow = out + (size_t)row * EMB;
#pragma unroll
    for (int i = 0; i < 3; i++) {
        int c = i * 256 + lane * 4;
        float4 gg = *reinterpret_cast<const float4*>(g + c);
        float4 bb = *reinterpret_cast<const float4*>(b + c);
        ushort4 o;
        o.x = f2b((vv[i].x - mu) * rstd * gg.x + bb.x);
        o.y = f2b((vv[i].y - mu) * rstd * gg.y + bb.y);
        o.z = f2b((vv[i].z - mu) * rstd * gg.z + bb.z);
        o.w = f2b((vv[i].w - mu) * rstd * gg.w + bb.w);
        *reinterpret_cast<ushort4*>(orow + c) = o;
    }
}

// ---------------------------------------------------------------------------
// LayerNorm, bf16 input -> bf16 out (for x1 residual stream).
// ---------------------------------------------------------------------------
__global__ __launch_bounds__(256) void ln_bf16in_kernel(const ushort* __restrict__ x,
                                                        const float* __restrict__ g,
                                                        const float* __restrict__ b,
                                                        ushort* __restrict__ out) {
    int row  = blockIdx.x * 4 + (threadIdx.x >> 6);
    int lane = threadIdx.x & 63;
    const ushort* xr = x + (size_t)row * EMB;
    float v[12];
#pragma unroll
    for (int i = 0; i < 3; i++) {
        ushort4 u = *reinterpret_cast<const ushort4*>(xr + i * 256 + lane * 4);
        v[i * 4 + 0] = b2f(u.x); v[i * 4 + 1] = b2f(u.y);
        v[i * 4 + 2] = b2f(u.z); v[i * 4 + 3] = b2f(u.w);
    }
    float s = 0.f;
#pragma unroll
    for (int i = 0; i < 12; i++) s += v[i];
#pragma unroll
    for (int off = 32; off; off >>= 1) s += __shfl_xor(s, off);
    float mu = s * (1.0f / EMB);
    float ss = 0.f;
#pragma unroll
    for (int i = 0; i < 12; i++) { float d = v[i] - mu; ss += d * d; }
#pragma unroll
    for (int off = 32; off; off >>= 1) ss += __shfl_xor(ss, off);
    float rstd = rsqrtf(ss * (1.0f / EMB) + 1e-5f);
    ushort* orow = out + (size_t)row * EMB;
#pragma unroll
    for (int i = 0; i < 3; i++) {
        int c = i * 256 + lane * 4;
        float4 gg = *reinterpret_cast<const float4*>(g + c);
        float4 bb = *reinterpret_cast<const float4*>(b + c);
        ushort4 o;
        o.x = f2b((v[i * 4 + 0] - mu) * rstd * gg.x + bb.x);
        o.y = f2b((v[i * 4 + 1] - mu) * rstd * gg.y + bb.y);
        o.z = f2b((v[i * 4 + 2] - mu) * rstd * gg.z + bb.z);
        o.w = f2b((v[i * 4 + 3] - mu) * rstd * gg.w + bb.w);
        *reinterpret_cast<ushort4*>(orow + c) = o;
    }
}

// ---------------------------------------------------------------------------
// Weight convert+transpose: out[n][k] = bf16(in[k][n]); n in [0,Npad),
// zeros for n >= N. 32x32 tiles via LDS.
// ---------------------------------------------------------------------------
__global__ __launch_bounds__(256) void convt_kernel(const float* __restrict__ in,
                                                    ushort* __restrict__ out,
                                                    int K, int N, int Npad) {
    __shared__ float t[32][33];
    int n0 = blockIdx.x * 32, k0 = blockIdx.y * 32;
    int tx = threadIdx.x, ty = threadIdx.y;
#pragma unroll
    for (int i = 0; i < 32; i += 8) {
        int n = n0 + tx;
        t[ty + i][tx] = (n < N) ? in[(size_t)(k0 + ty + i) * N + n] : 0.f;
    }
    __syncthreads();
#pragma unroll
    for (int i = 0; i < 32; i += 8) {
        out[(size_t)(n0 + ty + i) * K + k0 + tx] = f2b(t[tx][ty + i]);
    }
}

// Variant padding K: out[n][k] for k in [0,Kpad), zero for k >= K.
__global__ __launch_bounds__(256) void convt_pad_kernel(const float* __restrict__ in,
                                                        ushort* __restrict__ out,
                                                        int K, int N, int Kpad) {
    __shared__ float t[32][33];
    int n0 = blockIdx.x * 32, k0 = blockIdx.y * 32;
    int tx = threadIdx.x, ty = threadIdx.y;
#pragma unroll
    for (int i = 0; i < 32; i += 8) {
        int k = k0 + ty + i;
        t[ty + i][tx] = (k < K) ? in[(size_t)k * N + n0 + tx] : 0.f;
    }
    __syncthreads();
#pragma unroll
    for (int i = 0; i < 32; i += 8) {
        out[(size_t)(n0 + ty + i) * Kpad + k0 + tx] = f2b(t[tx][ty + i]);
    }
}

// ---------------------------------------------------------------------------
// bf16 MFMA GEMM: C[M,Nn] = A[M,K](bf16) @ Bt[Npad,K](bf16)^T  (+ epilogue)
// 128x128 tile, BK=64, 4 waves (2x2), 4x4 16x16x32 fragments per wave.
// Double-buffered LDS (64 KB -> 2 blocks/CU) + counted-vmcnt pipeline (R6).
// EPI: 0 fp32 store; 1 fp32 +bias +f32 res; 2 bf16 gelu(+bias);
//      3 bf16 (+bias +f32 res); 4 fp32 (+bias +bf16 res).
// 1-D grid with bijective XCD-chunked swizzle (T1). gridDim.x % 8 == 0.
// ---------------------------------------------------------------------------
template <int EPI, bool MASKN>
__global__ __launch_bounds__(256) void gemm_mfma(const ushort* __restrict__ A,
                                                 const ushort* __restrict__ Bt,
                                                 void* __restrict__ Cout,
                                                 const float* __restrict__ bias,
                                                 const void* __restrict__ resv,
                                                 int M, int Nn, int K, int gx) {
    __shared__ ushort As[2][128 * 64];  // [row][k] swizzled: chunk c at slot c^(row&7)
    __shared__ ushort Bs[2][128 * 64];
    int tid  = threadIdx.x;
    int lane = tid & 63, wave = tid >> 6;
    int wm = wave >> 1, wn = wave & 1;

    int nwg = gridDim.x;
    int lin = blockIdx.x;
    int swz = (lin & 7) * (nwg >> 3) + (lin >> 3);
    int by = swz / gx, bx = swz - by * gx;
    int m0 = by * 128, n0 = bx * 128;

    floatx4 acc[4][4] = {};

    int srow = lane >> 3;
    int slot = lane & 7;
    int nt = K >> 6;

    auto STAGE = [&](int t, int bufi) {
        int k0 = t << 6;
#pragma unroll
        for (int r = 0; r < 4; r++) {
            int row = r * 32 + wave * 8 + srow;
            int c   = slot ^ (row & 7);
            const ushort* ga = A  + (size_t)(m0 + row) * K + k0 + c * 8;
            const ushort* gb = Bt + (size_t)(n0 + row) * K + k0 + c * 8;
            GLL16(ga, (char*)&As[bufi][0] + r * 4096 + wave * 1024);
            GLL16(gb, (char*)&Bs[bufi][0] + r * 4096 + wave * 1024);
        }
    };

    STAGE(0, 0);
    STAGE(1, 1);
    asm volatile("s_waitcnt vmcnt(8)" ::: "memory");
    __builtin_amdgcn_sched_barrier(0);
    __builtin_amdgcn_s_barrier();

    int cur = 0;
    for (int t = 0; t < nt; ++t) {
        short8 af[2][4], bfr[2][4];
#pragma unroll
        for (int ks = 0; ks < 2; ks++) {
#pragma unroll
            for (int mi = 0; mi < 4; mi++) {
                int row = wm * 64 + mi * 16 + (lane & 15);
                int c   = ks * 4 + (lane >> 4);
                af[ks][mi] = *(const short8*)(&As[cur][0] + row * 64 + (c ^ (row & 7)) * 8);
            }
#pragma unroll
            for (int ni = 0; ni < 4; ni++) {
                int col = wn * 64 + ni * 16 + (lane & 15);
                int c   = ks * 4 + (lane >> 4);
                bfr[ks][ni] = *(const short8*)(&Bs[cur][0] + col * 64 + (c ^ (col & 7)) * 8);
            }
        }
        asm volatile("s_waitcnt lgkmcnt(0)" ::: "memory");
        __builtin_amdgcn_s_barrier();           // buf[cur] now dead for all waves
        __builtin_amdgcn_sched_barrier(0);

        int tn = t + 2; if (tn > nt - 1) tn = nt - 1;
        STAGE(tn, cur);

        asm volatile("s_waitcnt vmcnt(8)" ::: "memory");
        __builtin_amdgcn_sched_barrier(0);

#pragma unroll
        for (int ks = 0; ks < 2; ks++)
#pragma unroll
            for (int mi = 0; mi < 4; mi++)
#pragma unroll
                for (int ni = 0; ni < 4; ni++)
                    acc[mi][ni] = MFMA32(af[ks][mi], bfr[ks][ni], acc[mi][ni]);

        __builtin_amdgcn_s_barrier();
        __builtin_amdgcn_sched_barrier(0);
        cur ^= 1;
    }

    int r0 = m0 + wm * 64 + (lane >> 4) * 4;
    int c0 = n0 + wn * 64 + (lane & 15);
#pragma unroll
    for (int mi = 0; mi < 4; mi++) {
#pragma unroll
        for (int ni = 0; ni < 4; ni++) {
            int col = c0 + ni * 16;
            if (MASKN && col >= Nn) continue;
#pragma unroll
            for (int r = 0; r < 4; r++) {
                int row = r0 + mi * 16 + r;
                size_t idx = (size_t)row * Nn + col;
                float v = acc[mi][ni][r];
                if constexpr (EPI == 0) {
                    ((float*)Cout)[idx] = v;
                } else if constexpr (EPI == 1) {
                    ((float*)Cout)[idx] = v + bias[col] + ((const float*)resv)[idx];
                } else if constexpr (EPI == 2) {
                    ((ushort*)Cout)[idx] = f2b(gelu_f(v + bias[col]));
                } else if constexpr (EPI == 3) {
                    ((ushort*)Cout)[idx] = f2b(v + bias[col] + ((const float*)resv)[idx]);
                } else {
                    ((float*)Cout)[idx] = v + bias[col] + b2f(((const ushort*)resv)[idx]);
                }
            }
        }
    }
}

// ---------------------------------------------------------------------------
// MFMA attention. Block = (bh, 128-q group); 512 blocks, 256 thr (4 waves),
// each wave owns 2 q-tiles of 16. K staged bf16 [1024][12], V^T bf16
// [12][1032]. S^T = mfma16(K,Q); P^T C-layout == B-frag layout -> PV direct.
// Output: ao bf16 [8192][128]; h==0 blocks also zero-fill pad cols 96..127.
// ---------------------------------------------------------------------------
__global__ __launch_bounds__(256) void attn_mfma_kernel(const float* __restrict__ qkv,
                                                        ushort* __restrict__ ao) {
    __shared__ ushort Kt[NSEQ * 12];     // [j][d]
    __shared__ ushort VT[12 * 1032];     // [d][j], stride 1032
    int bh = blockIdx.x >> 3, qg = blockIdx.x & 7;
    int b = bh >> 3, h = bh & 7;
    int tid = threadIdx.x;
    const float* base = qkv + (size_t)b * NSEQ * (3 * INNER);

    // Pad zero-fill (replaces memset): h==0 blocks own cols 96..127 of their rows.
    if (h == 0) {
        ushort4 z; z.x = 0; z.y = 0; z.z = 0; z.w = 0;
        for (int s = tid; s < 128 * 8; s += 256) {
            int r = s >> 3, c = s & 7;
            *reinterpret_cast<ushort4*>(
                &ao[((size_t)(b * NSEQ + qg * 128 + r)) * 128 + 96 + c * 4]) = z;
        }
    }

#pragma unroll
    for (int i = 0; i < 4; i++) {
        int j = i * 256 + tid;
        const float* kp = base + (size_t)j * (3 * INNER) + INNER + h * HEAD_D;
        float4 a0 = *(const float4*)(kp);
        float4 a1 = *(const float4*)(kp + 4);
        float4 a2 = *(const float4*)(kp + 8);
        uint2* kw = (uint2*)(&Kt[j * 12]);
        kw[0] = make_uint2(pk2(a0.x, a0.y), pk2(a0.z, a0.w));
        kw[1] = make_uint2(pk2(a1.x, a1.y), pk2(a1.z, a1.w));
        kw[2] = make_uint2(pk2(a2.x, a2.y), pk2(a2.z, a2.w));
        const float* vp = kp + INNER;
        float4 v0 = *(const float4*)(vp);
        float4 v1 = *(const float4*)(vp + 4);
        float4 v2 = *(const float4*)(vp + 8);
        VT[0 * 1032 + j] = f2b(v0.x);  VT[1 * 1032 + j]  = f2b(v0.y);
        VT[2 * 1032 + j] = f2b(v0.z);  VT[3 * 1032 + j]  = f2b(v0.w);
        VT[4 * 1032 + j] = f2b(v1.x);  VT[5 * 1032 + j]  = f2b(v1.y);
        VT[6 * 1032 + j] = f2b(v1.z);  VT[7 * 1032 + j]  = f2b(v1.w);
        VT[8 * 1032 + j] = f2b(v2.x);  VT[9 * 1032 + j]  = f2b(v2.y);
        VT[10 * 1032 + j] = f2b(v2.z); VT[11 * 1032 + j] = f2b(v2.w);
    }
    __syncthreads();

    int lane = tid & 63, wave = tid >> 6;
    int qrow = lane & 15, grp = lane >> 4;
    const float scale = 0.102062072615966f;  // 96^-0.5

    s4b qf[2];
#pragma unroll
    for (int t = 0; t < 2; t++) {
        qf[t] = (s4b)0;
        if (grp < 3) {
            int q = qg * 128 + (wave * 2 + t) * 16 + qrow;
            const float* qp = base + (size_t)q * (3 * INNER) + h * HEAD_D + grp * 4;
            float4 qv = *(const float4*)(qp);
            uint2 u = make_uint2(pk2(qv.x * scale, qv.y * scale),
                                 pk2(qv.z * scale, qv.w * scale));
            qf[t] = __builtin_bit_cast(s4b, u);
        }
    }

    floatx4 acc[2] = {};
    float l[2] = {0.f, 0.f};
    int kc = (grp < 3) ? grp : 0;
    int dv = (qrow < 12) ? qrow : 0;
    bool kz = (grp == 3), vz = (qrow >= 12);
    const floatx4 z4 = {};

    for (int jt = 0; jt < 64; jt++) {
        s4b kf = *(const s4b*)(&Kt[(jt * 16 + qrow) * 12 + kc * 4]);
        if (kz) kf = (s4b)0;
        s4b vf = *(const s4b*)(&VT[dv * 1032 + jt * 16 + grp * 4]);
        if (vz) vf = (s4b)0;
#pragma unroll
        for (int t = 0; t < 2; t++) {
            floatx4 st = mfma16(kf, qf[t], z4);
            float p0 = __expf(st[0]), p1 = __expf(st[1]);
            float p2 = __expf(st[2]), p3 = __expf(st[3]);
            l[t] += (p0 + p1) + (p2 + p3);
            uint2 u = make_uint2(pk2(p0, p1), pk2(p2, p3));
            acc[t] = mfma16(vf, __builtin_bit_cast(s4b, u), acc[t]);
        }
    }

#pragma unroll
    for (int t = 0; t < 2; t++) {
        float lt = l[t];
        lt += __shfl_xor(lt, 16);
        lt += __shfl_xor(lt, 32);
        float inv = 1.f / lt;
        if (grp < 3) {
            int q = qg * 128 + (wave * 2 + t) * 16 + qrow;
            ushort4 o;
            o.x = f2b(acc[t][0] * inv);
            o.y = f2b(acc[t][1] * inv);
            o.z = f2b(acc[t][2] * inv);
            o.w = f2b(acc[t][3] * inv);
            *reinterpret_cast<ushort4*>(&ao[(size_t)(b * NSEQ + q) * 128 + h * HEAD_D + grp * 4]) = o;
        }
    }
}

// ---------------------------------------------------------------------------
// Launch
// ---------------------------------------------------------------------------
extern "C" void kernel_launch(void* const* d_in, const int* in_sizes, int n_in,
                              void* d_out, int out_size, void* d_ws, size_t ws_size,
                              hipStream_t stream) {
    const float* inputs = (const float*)d_in[0];
    const float* ln1_g  = (const float*)d_in[3];
    const float* ln1_b  = (const float*)d_in[4];
    const float* w_qkv  = (const float*)d_in[5];
    const float* w_proj = (const float*)d_in[6];
    const float* b_proj = (const float*)d_in[7];
    const float* ln2_g  = (const float*)d_in[8];
    const float* ln2_b  = (const float*)d_in[9];
    const float* w1     = (const float*)d_in[10];
    const float* b1     = (const float*)d_in[11];
    const float* w2     = (const float*)d_in[12];
    const float* b2     = (const float*)d_in[13];
    float* out = (float*)d_out;

    // Workspace layout (bytes):
    //  h_bf    : 8192*768*2   = 12,582,912  @ 0
    //  qkv     : 8192*288*4   =  9,437,184  @ 12,582,912
    //  ao_pad  : 8192*128*2   =  2,097,152  @ 22,020,096  (bf16, K-padded)
    //  wproj_t : 768*128*2    =    196,608  @ 24,117,248
    //  x1      : 8192*768*2   = 12,582,912  @ 25,165,824  (bf16 residual)
    //  m2      : 8192*3072*2  = 50,331,648  @ 50,331,648
    //  wqkv_t  : 384*768*2    =    589,824  @ 100,663,296
    //  w1_t    : 3072*768*2   =  4,718,592  @ 101,253,120
    //  w2_t    : 768*3072*2   =  4,718,592  @ 105,971,712
    char* ws = (char*)d_ws;
    ushort* h_bf    = (ushort*)(ws);
    float*  qkv     = (float*)(ws + 12582912);
    ushort* ao_pad  = (ushort*)(ws + 22020096);
    ushort* wproj_t = (ushort*)(ws + 24117248);
    ushort* x1      = (ushort*)(ws + 25165824);
    ushort* m2      = (ushort*)(ws + 50331648);
    ushort* wqkv_t  = (ushort*)(ws + 100663296);
    ushort* w1_t    = (ushort*)(ws + 101253120);
    ushort* w2_t    = (ushort*)(ws + 105971712);

    dim3 tb(32, 8);
    convt_kernel<<<dim3(12, 24), tb, 0, stream>>>(w_qkv, wqkv_t, EMB, 3 * INNER, 384);
    convt_kernel<<<dim3(96, 24), tb, 0, stream>>>(w1, w1_t, EMB, MLP_DIM, MLP_DIM);
    convt_kernel<<<dim3(24, 96), tb, 0, stream>>>(w2, w2_t, MLP_DIM, EMB, EMB);
    convt_pad_kernel<<<dim3(24, 4), tb, 0, stream>>>(w_proj, wproj_t, INNER, EMB, 128);

    // 1) LN1 -> bf16
    ln_f32in_kernel<<<ROWS / 4, 256, 0, stream>>>(inputs, ln1_g, ln1_b, h_bf);
    // 2) qkv = h @ w_qkv   [8192,288] K=768 (Npad=384); grid 3x64=192 (%8==0)
    gemm_mfma<0, true><<<3 * (ROWS / 128), 256, 0, stream>>>(
        h_bf, wqkv_t, qkv, nullptr, nullptr, ROWS, 3 * INNER, EMB, 3);
    // 3) attention -> ao_pad bf16 [8192,128] (pad cols zeroed by h==0 blocks)
    attn_mfma_kernel<<<512, 256, 0, stream>>>(qkv, ao_pad);
    // 4) x1 = bf16(inputs + ao @ w_proj + b_proj)   [8192,768] K=128(pad)
    gemm_mfma<3, false><<<6 * (ROWS / 128), 256, 0, stream>>>(
        ao_pad, wproj_t, x1, b_proj, inputs, ROWS, EMB, 128, 6);
    // 5) LN2 (bf16 in) -> bf16
    ln_bf16in_kernel<<<ROWS / 4, 256, 0, stream>>>(x1, ln2_g, ln2_b, h_bf);
    // 6) m2 = gelu(h @ w1 + b1) -> bf16   [8192,3072] K=768; grid 24x64=1536
    gemm_mfma<2, false><<<24 * (ROWS / 128), 256, 0, stream>>>(
        h_bf, w1_t, m2, b1, nullptr, ROWS, MLP_DIM, EMB, 24);
    // 7) out = bf16res(x1) + m2 @ w2 + b2 -> fp32   [8192,768] K=3072
    gemm_mfma<4, false><<<6 * (ROWS / 128), 256, 0, stream>>>(
        m2, w2_t, out, b2, x1, ROWS, EMB, MLP_DIM, 6);
}

// Round 13
// 182.440 us; speedup vs baseline: 2.5796x; 1.0199x over previous
//
#include <hip/hip_runtime.h>
#include <hip/hip_bf16.h>
#include <math.h>

// Problem constants
#define BB 8
#define NSEQ 1024
#define EMB 768
#define HEADS 8
#define INNER 96
#define HEAD_D 12
#define MLP_DIM 3072
#define ROWS (BB * NSEQ)   // 8192

using short8  = __attribute__((ext_vector_type(8))) short;
using s4b     = __attribute__((ext_vector_type(4))) short;
using floatx4 = __attribute__((ext_vector_type(4))) float;

// global -> LDS async copy, 16 B per lane. LDS dest must be wave-uniform base;
// HW adds lane*16. Global source is per-lane.
#define GLL16(g, l)                                                          \
    __builtin_amdgcn_global_load_lds(                                        \
        (const __attribute__((address_space(1))) void*)(g),                  \
        (__attribute__((address_space(3))) void*)(l), 16, 0, 0)

static __device__ __forceinline__ ushort f2b(float x) {
    __hip_bfloat16 h = __float2bfloat16(x);
    return *reinterpret_cast<ushort*>(&h);
}
static __device__ __forceinline__ float b2f(ushort u) {
    return __uint_as_float(((uint)u) << 16);
}
static __device__ __forceinline__ uint pk2(float a, float b) {
    return (uint)f2b(a) | ((uint)f2b(b) << 16);
}

// 16x16x16 bf16 MFMA (a,b: 4 bf16 = 2 VGPR; c/d: 4 f32)
static __device__ __forceinline__ floatx4 mfma16(s4b a, s4b b, floatx4 c) {
#if __has_builtin(__builtin_amdgcn_mfma_f32_16x16x16_bf16)
    return __builtin_amdgcn_mfma_f32_16x16x16_bf16(a, b, c, 0, 0, 0);
#elif __has_builtin(__builtin_amdgcn_mfma_f32_16x16x16bf16_1k)
    return __builtin_amdgcn_mfma_f32_16x16x16bf16_1k(a, b, c, 0, 0, 0);
#else
    floatx4 d;
    asm("v_mfma_f32_16x16x16_bf16 %0, %1, %2, %3" : "=v"(d) : "v"(a), "v"(b), "v"(c));
    return d;
#endif
}
#define MFMA32(a, b, c) __builtin_amdgcn_mfma_f32_16x16x32_bf16((a), (b), (c), 0, 0, 0)

static __device__ __forceinline__ float gelu_f(float v) {
    // tanh-GELU via sigmoid; |err| ~3e-4 << bf16 rounding.
    float u = v * (1.0f + 0.044715f * v * v);
    return v / (1.0f + __expf(-1.5957691216057308f * u));
}

// ---------------------------------------------------------------------------
// LayerNorm, fp32 input -> bf16 out. One wave per row of 768; vectorized
// float4 loads (16B/lane) + ushort4 stores (8B/lane). 4 rows / block.
// ---------------------------------------------------------------------------
__global__ __launch_bounds__(256) void ln_f32in_kernel(const float* __restrict__ x,
                                                       const float* __restrict__ g,
                                                       const float* __restrict__ b,
                                                       ushort* __restrict__ out) {
    int row  = blockIdx.x * 4 + (threadIdx.x >> 6);
    int lane = threadIdx.x & 63;
    const float* xr = x + (size_t)row * EMB;
    float4 vv[3];
#pragma unroll
    for (int i = 0; i < 3; i++)
        vv[i] = *reinterpret_cast<const float4*>(xr + i * 256 + lane * 4);
    float s = 0.f;
#pragma unroll
    for (int i = 0; i < 3; i++) s += (vv[i].x + vv[i].y) + (vv[i].z + vv[i].w);
#pragma unroll
    for (int off = 32; off; off >>= 1) s += __shfl_xor(s, off);
    float mu = s * (1.0f / EMB);
    float ss = 0.f;
#pragma unroll
    for (int i = 0; i < 3; i++) {
        float d0 = vv[i].x - mu, d1 = vv[i].y - mu, d2 = vv[i].z - mu, d3 = vv[i].w - mu;
        ss += (d0 * d0 + d1 * d1) + (d2 * d2 + d3 * d3);
    }
#pragma unroll
    for (int off = 32; off; off >>= 1) ss += __shfl_xor(ss, off);
    float rstd = rsqrtf(ss * (1.0f / EMB) + 1e-5f);
    ushort* orow = out + (size_t)row * EMB;
#pragma unroll
    for (int i = 0; i < 3; i++) {
        int c = i * 256 + lane * 4;
        float4 gg = *reinterpret_cast<const float4*>(g + c);
        float4 bb = *reinterpret_cast<const float4*>(b + c);
        ushort4 o;
        o.x = f2b((vv[i].x - mu) * rstd * gg.x + bb.x);
        o.y = f2b((vv[i].y - mu) * rstd * gg.y + bb.y);
        o.z = f2b((vv[i].z - mu) * rstd * gg.z + bb.z);
        o.w = f2b((vv[i].w - mu) * rstd * gg.w + bb.w);
        *reinterpret_cast<ushort4*>(orow + c) = o;
    }
}

// ---------------------------------------------------------------------------
// LayerNorm, bf16 input -> bf16 out (for x1 residual stream).
// ---------------------------------------------------------------------------
__global__ __launch_bounds__(256) void ln_bf16in_kernel(const ushort* __restrict__ x,
                                                        const float* __restrict__ g,
                                                        const float* __restrict__ b,
                                                        ushort* __restrict__ out) {
    int row  = blockIdx.x * 4 + (threadIdx.x >> 6);
    int lane = threadIdx.x & 63;
    const ushort* xr = x + (size_t)row * EMB;
    float v[12];
#pragma unroll
    for (int i = 0; i < 3; i++) {
        ushort4 u = *reinterpret_cast<const ushort4*>(xr + i * 256 + lane * 4);
        v[i * 4 + 0] = b2f(u.x); v[i * 4 + 1] = b2f(u.y);
        v[i * 4 + 2] = b2f(u.z); v[i * 4 + 3] = b2f(u.w);
    }
    float s = 0.f;
#pragma unroll
    for (int i = 0; i < 12; i++) s += v[i];
#pragma unroll
    for (int off = 32; off; off >>= 1) s += __shfl_xor(s, off);
    float mu = s * (1.0f / EMB);
    float ss = 0.f;
#pragma unroll
    for (int i = 0; i < 12; i++) { float d = v[i] - mu; ss += d * d; }
#pragma unroll
    for (int off = 32; off; off >>= 1) ss += __shfl_xor(ss, off);
    float rstd = rsqrtf(ss * (1.0f / EMB) + 1e-5f);
    ushort* orow = out + (size_t)row * EMB;
#pragma unroll
    for (int i = 0; i < 3; i++) {
        int c = i * 256 + lane * 4;
        float4 gg = *reinterpret_cast<const float4*>(g + c);
        float4 bb = *reinterpret_cast<const float4*>(b + c);
        ushort4 o;
        o.x = f2b((v[i * 4 + 0] - mu) * rstd * gg.x + bb.x);
        o.y = f2b((v[i * 4 + 1] - mu) * rstd * gg.y + bb.y);
        o.z = f2b((v[i * 4 + 2] - mu) * rstd * gg.z + bb.z);
        o.w = f2b((v[i * 4 + 3] - mu) * rstd * gg.w + bb.w);
        *reinterpret_cast<ushort4*>(orow + c) = o;
    }
}

// ---------------------------------------------------------------------------
// Weight convert+transpose: out[n][k] = bf16(in[k][n]); n in [0,Npad),
// zeros for n >= N. 32x32 tiles via LDS.
// ---------------------------------------------------------------------------
__global__ __launch_bounds__(256) void convt_kernel(const float* __restrict__ in,
                                                    ushort* __restrict__ out,
                                                    int K, int N, int Npad) {
    __shared__ float t[32][33];
    int n0 = blockIdx.x * 32, k0 = blockIdx.y * 32;
    int tx = threadIdx.x, ty = threadIdx.y;
#pragma unroll
    for (int i = 0; i < 32; i += 8) {
        int n = n0 + tx;
        t[ty + i][tx] = (n < N) ? in[(size_t)(k0 + ty + i) * N + n] : 0.f;
    }
    __syncthreads();
#pragma unroll
    for (int i = 0; i < 32; i += 8) {
        out[(size_t)(n0 + ty + i) * K + k0 + tx] = f2b(t[tx][ty + i]);
    }
}

// Variant padding K: out[n][k] for k in [0,Kpad), zero for k >= K.
__global__ __launch_bounds__(256) void convt_pad_kernel(const float* __restrict__ in,
                                                        ushort* __restrict__ out,
                                                        int K, int N, int Kpad) {
    __shared__ float t[32][33];
    int n0 = blockIdx.x * 32, k0 = blockIdx.y * 32;
    int tx = threadIdx.x, ty = threadIdx.y;
#pragma unroll
    for (int i = 0; i < 32; i += 8) {
        int k = k0 + ty + i;
        t[ty + i][tx] = (k < K) ? in[(size_t)k * N + n0 + tx] : 0.f;
    }
    __syncthreads();
#pragma unroll
    for (int i = 0; i < 32; i += 8) {
        out[(size_t)(n0 + ty + i) * Kpad + k0 + tx] = f2b(t[tx][ty + i]);
    }
}

// ---------------------------------------------------------------------------
// bf16 MFMA GEMM: C[M,Nn] = A[M,K](bf16) @ Bt[Npad,K](bf16)^T  (+ epilogue)
// 128x128 tile, BK=64, 4 waves (2x2), 4x4 16x16x32 fragments per wave.
// Double-buffered LDS (64 KB -> 2 blocks/CU) + counted-vmcnt pipeline (R6)
// with tail-stage guard: no redundant re-stage in the last 2 iterations;
// tail gate degrades to vmcnt(0) (loads issued a full iteration earlier).
// EPI: 0 fp32 store; 1 fp32 +bias +f32 res; 2 bf16 gelu(+bias);
//      3 bf16 (+bias +f32 res); 4 fp32 (+bias +bf16 res).
// 1-D grid with bijective XCD-chunked swizzle (T1). gridDim.x % 8 == 0.
// ---------------------------------------------------------------------------
template <int EPI, bool MASKN>
__global__ __launch_bounds__(256) void gemm_mfma(const ushort* __restrict__ A,
                                                 const ushort* __restrict__ Bt,
                                                 void* __restrict__ Cout,
                                                 const float* __restrict__ bias,
                                                 const void* __restrict__ resv,
                                                 int M, int Nn, int K, int gx) {
    __shared__ ushort As[2][128 * 64];  // [row][k] swizzled: chunk c at slot c^(row&7)
    __shared__ ushort Bs[2][128 * 64];
    int tid  = threadIdx.x;
    int lane = tid & 63, wave = tid >> 6;
    int wm = wave >> 1, wn = wave & 1;

    int nwg = gridDim.x;
    int lin = blockIdx.x;
    int swz = (lin & 7) * (nwg >> 3) + (lin >> 3);
    int by = swz / gx, bx = swz - by * gx;
    int m0 = by * 128, n0 = bx * 128;

    floatx4 acc[4][4] = {};

    int srow = lane >> 3;
    int slot = lane & 7;
    int nt = K >> 6;

    auto STAGE = [&](int t, int bufi) {
        int k0 = t << 6;
#pragma unroll
        for (int r = 0; r < 4; r++) {
            int row = r * 32 + wave * 8 + srow;
            int c   = slot ^ (row & 7);
            const ushort* ga = A  + (size_t)(m0 + row) * K + k0 + c * 8;
            const ushort* gb = Bt + (size_t)(n0 + row) * K + k0 + c * 8;
            GLL16(ga, (char*)&As[bufi][0] + r * 4096 + wave * 1024);
            GLL16(gb, (char*)&Bs[bufi][0] + r * 4096 + wave * 1024);
        }
    };

    STAGE(0, 0);
    STAGE(1, 1);
    asm volatile("s_waitcnt vmcnt(8)" ::: "memory");
    __builtin_amdgcn_sched_barrier(0);
    __builtin_amdgcn_s_barrier();

    int cur = 0;
    for (int t = 0; t < nt; ++t) {
        short8 af[2][4], bfr[2][4];
#pragma unroll
        for (int ks = 0; ks < 2; ks++) {
#pragma unroll
            for (int mi = 0; mi < 4; mi++) {
                int row = wm * 64 + mi * 16 + (lane & 15);
                int c   = ks * 4 + (lane >> 4);
                af[ks][mi] = *(const short8*)(&As[cur][0] + row * 64 + (c ^ (row & 7)) * 8);
            }
#pragma unroll
            for (int ni = 0; ni < 4; ni++) {
                int col = wn * 64 + ni * 16 + (lane & 15);
                int c   = ks * 4 + (lane >> 4);
                bfr[ks][ni] = *(const short8*)(&Bs[cur][0] + col * 64 + (c ^ (col & 7)) * 8);
            }
        }
        asm volatile("s_waitcnt lgkmcnt(0)" ::: "memory");
        __builtin_amdgcn_s_barrier();           // buf[cur] now dead for all waves
        __builtin_amdgcn_sched_barrier(0);

        // stage tile t+2 into the dead buffer (only if it exists)
        bool st = (t + 2) < nt;
        if (st) STAGE(t + 2, cur);

        // counted gate: tile t+1's 8 loads landed; t+2's (if any) stay in flight
        if (st) asm volatile("s_waitcnt vmcnt(8)" ::: "memory");
        else    asm volatile("s_waitcnt vmcnt(0)" ::: "memory");
        __builtin_amdgcn_sched_barrier(0);

#pragma unroll
        for (int ks = 0; ks < 2; ks++)
#pragma unroll
            for (int mi = 0; mi < 4; mi++)
#pragma unroll
                for (int ni = 0; ni < 4; ni++)
                    acc[mi][ni] = MFMA32(af[ks][mi], bfr[ks][ni], acc[mi][ni]);

        __builtin_amdgcn_s_barrier();
        __builtin_amdgcn_sched_barrier(0);
        cur ^= 1;
    }

    int r0 = m0 + wm * 64 + (lane >> 4) * 4;
    int c0 = n0 + wn * 64 + (lane & 15);
#pragma unroll
    for (int mi = 0; mi < 4; mi++) {
#pragma unroll
        for (int ni = 0; ni < 4; ni++) {
            int col = c0 + ni * 16;
            if (MASKN && col >= Nn) continue;
#pragma unroll
            for (int r = 0; r < 4; r++) {
                int row = r0 + mi * 16 + r;
                size_t idx = (size_t)row * Nn + col;
                float v = acc[mi][ni][r];
                if constexpr (EPI == 0) {
                    ((float*)Cout)[idx] = v;
                } else if constexpr (EPI == 1) {
                    ((float*)Cout)[idx] = v + bias[col] + ((const float*)resv)[idx];
                } else if constexpr (EPI == 2) {
                    ((ushort*)Cout)[idx] = f2b(gelu_f(v + bias[col]));
                } else if constexpr (EPI == 3) {
                    ((ushort*)Cout)[idx] = f2b(v + bias[col] + ((const float*)resv)[idx]);
                } else {
                    ((float*)Cout)[idx] = v + bias[col] + b2f(((const ushort*)resv)[idx]);
                }
            }
        }
    }
}

// ---------------------------------------------------------------------------
// MFMA attention. Block = (bh, 128-q group); 512 blocks, 256 thr (4 waves),
// each wave owns 2 q-tiles of 16. K staged bf16 [1024][12], V^T bf16
// [12][1032]. S^T = mfma16(K,Q); P^T C-layout == B-frag layout -> PV direct.
// Output: ao bf16 [8192][128]; h==0 blocks also zero-fill pad cols 96..127.
// ---------------------------------------------------------------------------
__global__ __launch_bounds__(256) void attn_mfma_kernel(const float* __restrict__ qkv,
                                                        ushort* __restrict__ ao) {
    __shared__ ushort Kt[NSEQ * 12];     // [j][d]
    __shared__ ushort VT[12 * 1032];     // [d][j], stride 1032
    int bh = blockIdx.x >> 3, qg = blockIdx.x & 7;
    int b = bh >> 3, h = bh & 7;
    int tid = threadIdx.x;
    const float* base = qkv + (size_t)b * NSEQ * (3 * INNER);

    // Pad zero-fill (replaces memset): h==0 blocks own cols 96..127 of their rows.
    if (h == 0) {
        ushort4 z; z.x = 0; z.y = 0; z.z = 0; z.w = 0;
        for (int s = tid; s < 128 * 8; s += 256) {
            int r = s >> 3, c = s & 7;
            *reinterpret_cast<ushort4*>(
                &ao[((size_t)(b * NSEQ + qg * 128 + r)) * 128 + 96 + c * 4]) = z;
        }
    }

#pragma unroll
    for (int i = 0; i < 4; i++) {
        int j = i * 256 + tid;
        const float* kp = base + (size_t)j * (3 * INNER) + INNER + h * HEAD_D;
        float4 a0 = *(const float4*)(kp);
        float4 a1 = *(const float4*)(kp + 4);
        float4 a2 = *(const float4*)(kp + 8);
        uint2* kw = (uint2*)(&Kt[j * 12]);
        kw[0] = make_uint2(pk2(a0.x, a0.y), pk2(a0.z, a0.w));
        kw[1] = make_uint2(pk2(a1.x, a1.y), pk2(a1.z, a1.w));
        kw[2] = make_uint2(pk2(a2.x, a2.y), pk2(a2.z, a2.w));
        const float* vp = kp + INNER;
        float4 v0 = *(const float4*)(vp);
        float4 v1 = *(const float4*)(vp + 4);
        float4 v2 = *(const float4*)(vp + 8);
        VT[0 * 1032 + j] = f2b(v0.x);  VT[1 * 1032 + j]  = f2b(v0.y);
        VT[2 * 1032 + j] = f2b(v0.z);  VT[3 * 1032 + j]  = f2b(v0.w);
        VT[4 * 1032 + j] = f2b(v1.x);  VT[5 * 1032 + j]  = f2b(v1.y);
        VT[6 * 1032 + j] = f2b(v1.z);  VT[7 * 1032 + j]  = f2b(v1.w);
        VT[8 * 1032 + j] = f2b(v2.x);  VT[9 * 1032 + j]  = f2b(v2.y);
        VT[10 * 1032 + j] = f2b(v2.z); VT[11 * 1032 + j] = f2b(v2.w);
    }
    __syncthreads();

    int lane = tid & 63, wave = tid >> 6;
    int qrow = lane & 15, grp = lane >> 4;
    const float scale = 0.102062072615966f;  // 96^-0.5

    s4b qf[2];
#pragma unroll
    for (int t = 0; t < 2; t++) {
        qf[t] = (s4b)0;
        if (grp < 3) {
            int q = qg * 128 + (wave * 2 + t) * 16 + qrow;
            const float* qp = base + (size_t)q * (3 * INNER) + h * HEAD_D + grp * 4;
            float4 qv = *(const float4*)(qp);
            uint2 u = make_uint2(pk2(qv.x * scale, qv.y * scale),
                                 pk2(qv.z * scale, qv.w * scale));
            qf[t] = __builtin_bit_cast(s4b, u);
        }
    }

    floatx4 acc[2] = {};
    float l[2] = {0.f, 0.f};
    int kc = (grp < 3) ? grp : 0;
    int dv = (qrow < 12) ? qrow : 0;
    bool kz = (grp == 3), vz = (qrow >= 12);
    const floatx4 z4 = {};

    for (int jt = 0; jt < 64; jt++) {
        s4b kf = *(const s4b*)(&Kt[(jt * 16 + qrow) * 12 + kc * 4]);
        if (kz) kf = (s4b)0;
        s4b vf = *(const s4b*)(&VT[dv * 1032 + jt * 16 + grp * 4]);
        if (vz) vf = (s4b)0;
#pragma unroll
        for (int t = 0; t < 2; t++) {
            floatx4 st = mfma16(kf, qf[t], z4);
            float p0 = __expf(st[0]), p1 = __expf(st[1]);
            float p2 = __expf(st[2]), p3 = __expf(st[3]);
            l[t] += (p0 + p1) + (p2 + p3);
            uint2 u = make_uint2(pk2(p0, p1), pk2(p2, p3));
            acc[t] = mfma16(vf, __builtin_bit_cast(s4b, u), acc[t]);
        }
    }

#pragma unroll
    for (int t = 0; t < 2; t++) {
        float lt = l[t];
        lt += __shfl_xor(lt, 16);
        lt += __shfl_xor(lt, 32);
        float inv = 1.f / lt;
        if (grp < 3) {
            int q = qg * 128 + (wave * 2 + t) * 16 + qrow;
            ushort4 o;
            o.x = f2b(acc[t][0] * inv);
            o.y = f2b(acc[t][1] * inv);
            o.z = f2b(acc[t][2] * inv);
            o.w = f2b(acc[t][3] * inv);
            *reinterpret_cast<ushort4*>(&ao[(size_t)(b * NSEQ + q) * 128 + h * HEAD_D + grp * 4]) = o;
        }
    }
}

// ---------------------------------------------------------------------------
// Launch
// ---------------------------------------------------------------------------
extern "C" void kernel_launch(void* const* d_in, const int* in_sizes, int n_in,
                              void* d_out, int out_size, void* d_ws, size_t ws_size,
                              hipStream_t stream) {
    const float* inputs = (const float*)d_in[0];
    const float* ln1_g  = (const float*)d_in[3];
    const float* ln1_b  = (const float*)d_in[4];
    const float* w_qkv  = (const float*)d_in[5];
    const float* w_proj = (const float*)d_in[6];
    const float* b_proj = (const float*)d_in[7];
    const float* ln2_g  = (const float*)d_in[8];
    const float* ln2_b  = (const float*)d_in[9];
    const float* w1     = (const float*)d_in[10];
    const float* b1     = (const float*)d_in[11];
    const float* w2     = (const float*)d_in[12];
    const float* b2     = (const float*)d_in[13];
    float* out = (float*)d_out;

    // Workspace layout (bytes):
    //  h_bf    : 8192*768*2   = 12,582,912  @ 0
    //  qkv     : 8192*288*4   =  9,437,184  @ 12,582,912
    //  ao_pad  : 8192*128*2   =  2,097,152  @ 22,020,096  (bf16, K-padded)
    //  wproj_t : 768*128*2    =    196,608  @ 24,117,248
    //  x1      : 8192*768*2   = 12,582,912  @ 25,165,824  (bf16 residual)
    //  m2      : 8192*3072*2  = 50,331,648  @ 50,331,648
    //  wqkv_t  : 384*768*2    =    589,824  @ 100,663,296
    //  w1_t    : 3072*768*2   =  4,718,592  @ 101,253,120
    //  w2_t    : 768*3072*2   =  4,718,592  @ 105,971,712
    char* ws = (char*)d_ws;
    ushort* h_bf    = (ushort*)(ws);
    float*  qkv     = (float*)(ws + 12582912);
    ushort* ao_pad  = (ushort*)(ws + 22020096);
    ushort* wproj_t = (ushort*)(ws + 24117248);
    ushort* x1      = (ushort*)(ws + 25165824);
    ushort* m2      = (ushort*)(ws + 50331648);
    ushort* wqkv_t  = (ushort*)(ws + 100663296);
    ushort* w1_t    = (ushort*)(ws + 101253120);
    ushort* w2_t    = (ushort*)(ws + 105971712);

    dim3 tb(32, 8);
    convt_kernel<<<dim3(12, 24), tb, 0, stream>>>(w_qkv, wqkv_t, EMB, 3 * INNER, 384);
    convt_kernel<<<dim3(96, 24), tb, 0, stream>>>(w1, w1_t, EMB, MLP_DIM, MLP_DIM);
    convt_kernel<<<dim3(24, 96), tb, 0, stream>>>(w2, w2_t, MLP_DIM, EMB, EMB);
    convt_pad_kernel<<<dim3(24, 4), tb, 0, stream>>>(w_proj, wproj_t, INNER, EMB, 128);

    // 1) LN1 -> bf16
    ln_f32in_kernel<<<ROWS / 4, 256, 0, stream>>>(inputs, ln1_g, ln1_b, h_bf);
    // 2) qkv = h @ w_qkv   [8192,288] K=768 (Npad=384); grid 3x64=192 (%8==0)
    gemm_mfma<0, true><<<3 * (ROWS / 128), 256, 0, stream>>>(
        h_bf, wqkv_t, qkv, nullptr, nullptr, ROWS, 3 * INNER, EMB, 3);
    // 3) attention -> ao_pad bf16 [8192,128] (pad cols zeroed by h==0 blocks)
    attn_mfma_kernel<<<512, 256, 0, stream>>>(qkv, ao_pad);
    // 4) x1 = bf16(inputs + ao @ w_proj + b_proj)   [8192,768] K=128(pad)
    gemm_mfma<3, false><<<6 * (ROWS / 128), 256, 0, stream>>>(
        ao_pad, wproj_t, x1, b_proj, inputs, ROWS, EMB, 128, 6);
    // 5) LN2 (bf16 in) -> bf16
    ln_bf16in_kernel<<<ROWS / 4, 256, 0, stream>>>(x1, ln2_g, ln2_b, h_bf);
    // 6) m2 = gelu(h @ w1 + b1) -> bf16   [8192,3072] K=768; grid 24x64=1536
    gemm_mfma<2, false><<<24 * (ROWS / 128), 256, 0, stream>>>(
        h_bf, w1_t, m2, b1, nullptr, ROWS, MLP_DIM, EMB, 24);
    // 7) out = bf16res(x1) + m2 @ w2 + b2 -> fp32   [8192,768] K=3072
    gemm_mfma<4, false><<<6 * (ROWS / 128), 256, 0, stream>>>(
        m2, w2_t, out, b2, x1, ROWS, EMB, MLP_DIM, 6);
}

// Round 14
// 172.847 us; speedup vs baseline: 2.7228x; 1.0555x over previous
//
#include <hip/hip_runtime.h>
#include <hip/hip_bf16.h>
#include <math.h>

// Problem constants
#define BB 8
#define NSEQ 1024
#define EMB 768
#define HEADS 8
#define INNER 96
#define HEAD_D 12
#define MLP_DIM 3072
#define ROWS (BB * NSEQ)   // 8192

using short8  = __attribute__((ext_vector_type(8))) short;
using s4b     = __attribute__((ext_vector_type(4))) short;
using floatx4 = __attribute__((ext_vector_type(4))) float;

// global -> LDS async copy, 16 B per lane. LDS dest must be wave-uniform base;
// HW adds lane*16. Global source is per-lane.
#define GLL16(g, l)                                                          \
    __builtin_amdgcn_global_load_lds(                                        \
        (const __attribute__((address_space(1))) void*)(g),                  \
        (__attribute__((address_space(3))) void*)(l), 16, 0, 0)

static __device__ __forceinline__ ushort f2b(float x) {
    __hip_bfloat16 h = __float2bfloat16(x);
    return *reinterpret_cast<ushort*>(&h);
}
static __device__ __forceinline__ float b2f(ushort u) {
    return __uint_as_float(((uint)u) << 16);
}
static __device__ __forceinline__ uint pk2(float a, float b) {
    return (uint)f2b(a) | ((uint)f2b(b) << 16);
}

// 16x16x16 bf16 MFMA (a,b: 4 bf16 = 2 VGPR; c/d: 4 f32)
static __device__ __forceinline__ floatx4 mfma16(s4b a, s4b b, floatx4 c) {
#if __has_builtin(__builtin_amdgcn_mfma_f32_16x16x16_bf16)
    return __builtin_amdgcn_mfma_f32_16x16x16_bf16(a, b, c, 0, 0, 0);
#elif __has_builtin(__builtin_amdgcn_mfma_f32_16x16x16bf16_1k)
    return __builtin_amdgcn_mfma_f32_16x16x16bf16_1k(a, b, c, 0, 0, 0);
#else
    floatx4 d;
    asm("v_mfma_f32_16x16x16_bf16 %0, %1, %2, %3" : "=v"(d) : "v"(a), "v"(b), "v"(c));
    return d;
#endif
}
#define MFMA32(a, b, c) __builtin_amdgcn_mfma_f32_16x16x32_bf16((a), (b), (c), 0, 0, 0)

static __device__ __forceinline__ float gelu_f(float v) {
    // tanh-GELU via sigmoid; |err| ~3e-4 << bf16 rounding.
    float u = v * (1.0f + 0.044715f * v * v);
    return v / (1.0f + __expf(-1.5957691216057308f * u));
}

// ---------------------------------------------------------------------------
// LayerNorm, fp32 input -> bf16 out. One wave per row of 768; vectorized
// float4 loads (16B/lane) + ushort4 stores (8B/lane). 4 rows / block.
// ---------------------------------------------------------------------------
__global__ __launch_bounds__(256) void ln_f32in_kernel(const float* __restrict__ x,
                                                       const float* __restrict__ g,
                                                       const float* __restrict__ b,
                                                       ushort* __restrict__ out) {
    int row  = blockIdx.x * 4 + (threadIdx.x >> 6);
    int lane = threadIdx.x & 63;
    const float* xr = x + (size_t)row * EMB;
    float4 vv[3];
#pragma unroll
    for (int i = 0; i < 3; i++)
        vv[i] = *reinterpret_cast<const float4*>(xr + i * 256 + lane * 4);
    float s = 0.f;
#pragma unroll
    for (int i = 0; i < 3; i++) s += (vv[i].x + vv[i].y) + (vv[i].z + vv[i].w);
#pragma unroll
    for (int off = 32; off; off >>= 1) s += __shfl_xor(s, off);
    float mu = s * (1.0f / EMB);
    float ss = 0.f;
#pragma unroll
    for (int i = 0; i < 3; i++) {
        float d0 = vv[i].x - mu, d1 = vv[i].y - mu, d2 = vv[i].z - mu, d3 = vv[i].w - mu;
        ss += (d0 * d0 + d1 * d1) + (d2 * d2 + d3 * d3);
    }
#pragma unroll
    for (int off = 32; off; off >>= 1) ss += __shfl_xor(ss, off);
    float rstd = rsqrtf(ss * (1.0f / EMB) + 1e-5f);
    ushort* orow = out + (size_t)row * EMB;
#pragma unroll
    for (int i = 0; i < 3; i++) {
        int c = i * 256 + lane * 4;
        float4 gg = *reinterpret_cast<const float4*>(g + c);
        float4 bb = *reinterpret_cast<const float4*>(b + c);
        ushort4 o;
        o.x = f2b((vv[i].x - mu) * rstd * gg.x + bb.x);
        o.y = f2b((vv[i].y - mu) * rstd * gg.y + bb.y);
        o.z = f2b((vv[i].z - mu) * rstd * gg.z + bb.z);
        o.w = f2b((vv[i].w - mu) * rstd * gg.w + bb.w);
        *reinterpret_cast<ushort4*>(orow + c) = o;
    }
}

// ---------------------------------------------------------------------------
// LayerNorm, bf16 input -> bf16 out (for x1 residual stream).
// ---------------------------------------------------------------------------
__global__ __launch_bounds__(256) void ln_bf16in_kernel(const ushort* __restrict__ x,
                                                        const float* __restrict__ g,
                                                        const float* __restrict__ b,
                                                        ushort* __restrict__ out) {
    int row  = blockIdx.x * 4 + (threadIdx.x >> 6);
    int lane = threadIdx.x & 63;
    const ushort* xr = x + (size_t)row * EMB;
    float v[12];
#pragma unroll
    for (int i = 0; i < 3; i++) {
        ushort4 u = *reinterpret_cast<const ushort4*>(xr + i * 256 + lane * 4);
        v[i * 4 + 0] = b2f(u.x); v[i * 4 + 1] = b2f(u.y);
        v[i * 4 + 2] = b2f(u.z); v[i * 4 + 3] = b2f(u.w);
    }
    float s = 0.f;
#pragma unroll
    for (int i = 0; i < 12; i++) s += v[i];
#pragma unroll
    for (int off = 32; off; off >>= 1) s += __shfl_xor(s, off);
    float mu = s * (1.0f / EMB);
    float ss = 0.f;
#pragma unroll
    for (int i = 0; i < 12; i++) { float d = v[i] - mu; ss += d * d; }
#pragma unroll
    for (int off = 32; off; off >>= 1) ss += __shfl_xor(ss, off);
    float rstd = rsqrtf(ss * (1.0f / EMB) + 1e-5f);
    ushort* orow = out + (size_t)row * EMB;
#pragma unroll
    for (int i = 0; i < 3; i++) {
        int c = i * 256 + lane * 4;
        float4 gg = *reinterpret_cast<const float4*>(g + c);
        float4 bb = *reinterpret_cast<const float4*>(b + c);
        ushort4 o;
        o.x = f2b((v[i * 4 + 0] - mu) * rstd * gg.x + bb.x);
        o.y = f2b((v[i * 4 + 1] - mu) * rstd * gg.y + bb.y);
        o.z = f2b((v[i * 4 + 2] - mu) * rstd * gg.z + bb.z);
        o.w = f2b((v[i * 4 + 3] - mu) * rstd * gg.w + bb.w);
        *reinterpret_cast<ushort4*>(orow + c) = o;
    }
}

// ---------------------------------------------------------------------------
// Fused weight convert+transpose: one launch does all four weights.
// Block ranges: [0,2304) w1; [2304,4608) w2; [4608,4896) wqkv; [4896,4992)
// wproj (K-padded to 128). Body identical to the previous convt kernels.
// ---------------------------------------------------------------------------
__global__ __launch_bounds__(256) void convt_all_kernel(
    const float* __restrict__ w1,   ushort* __restrict__ w1_t,
    const float* __restrict__ w2,   ushort* __restrict__ w2_t,
    const float* __restrict__ wqkv, ushort* __restrict__ wqkv_t,
    const float* __restrict__ wprj, ushort* __restrict__ wprj_t) {
    __shared__ float t[32][33];
    int id = blockIdx.x;
    const float* in; ushort* out;
    int K, N, Kout, bx, by; bool padK = false;
    if (id < 2304)      { in = w1;   out = w1_t;   K = EMB;     N = MLP_DIM;   Kout = K;  bx = id % 96; by = id / 96; }
    else if (id < 4608) { id -= 2304; in = w2;   out = w2_t;   K = MLP_DIM; N = EMB;       Kout = K;  bx = id % 24; by = id / 24; }
    else if (id < 4896) { id -= 4608; in = wqkv; out = wqkv_t; K = EMB;     N = 3 * INNER; Kout = K;  bx = id % 12; by = id / 12; }
    else                { id -= 4896; in = wprj; out = wprj_t; K = INNER;   N = EMB;       Kout = 128; bx = id % 24; by = id / 24; padK = true; }
    int n0 = bx * 32, k0 = by * 32;
    int tx = threadIdx.x, ty = threadIdx.y;
    if (!padK) {
#pragma unroll
        for (int i = 0; i < 32; i += 8) {
            int n = n0 + tx;
            t[ty + i][tx] = (n < N) ? in[(size_t)(k0 + ty + i) * N + n] : 0.f;
        }
    } else {
#pragma unroll
        for (int i = 0; i < 32; i += 8) {
            int k = k0 + ty + i;
            t[ty + i][tx] = (k < K) ? in[(size_t)k * N + n0 + tx] : 0.f;
        }
    }
    __syncthreads();
#pragma unroll
    for (int i = 0; i < 32; i += 8) {
        out[(size_t)(n0 + ty + i) * Kout + k0 + tx] = f2b(t[tx][ty + i]);
    }
}

// ---------------------------------------------------------------------------
// bf16 MFMA GEMM: C[M,Nn] = A[M,K](bf16) @ Bt[Npad,K](bf16)^T  (+ epilogue)
// 128x128 tile, BK=64, 4 waves (2x2), 4x4 16x16x32 fragments per wave.
// Double-buffered LDS (64 KB -> 2 blocks/CU) + counted-vmcnt pipeline (R6)
// with tail-stage guard.
// EPI: 0 fp32 store; 1 fp32 +bias +f32 res; 2 bf16 gelu(+bias);
//      3 bf16 (+bias +f32 res); 4 fp32 (+bias +bf16 res);
//      5 bf16 store with softmax-scale folded into cols<96 (qkv).
// 1-D grid with bijective XCD-chunked swizzle (T1). gridDim.x % 8 == 0.
// ---------------------------------------------------------------------------
template <int EPI, bool MASKN>
__global__ __launch_bounds__(256) void gemm_mfma(const ushort* __restrict__ A,
                                                 const ushort* __restrict__ Bt,
                                                 void* __restrict__ Cout,
                                                 const float* __restrict__ bias,
                                                 const void* __restrict__ resv,
                                                 int M, int Nn, int K, int gx) {
    __shared__ ushort As[2][128 * 64];  // [row][k] swizzled: chunk c at slot c^(row&7)
    __shared__ ushort Bs[2][128 * 64];
    int tid  = threadIdx.x;
    int lane = tid & 63, wave = tid >> 6;
    int wm = wave >> 1, wn = wave & 1;

    int nwg = gridDim.x;
    int lin = blockIdx.x;
    int swz = (lin & 7) * (nwg >> 3) + (lin >> 3);
    int by = swz / gx, bx = swz - by * gx;
    int m0 = by * 128, n0 = bx * 128;

    floatx4 acc[4][4] = {};

    int srow = lane >> 3;
    int slot = lane & 7;
    int nt = K >> 6;

    auto STAGE = [&](int t, int bufi) {
        int k0 = t << 6;
#pragma unroll
        for (int r = 0; r < 4; r++) {
            int row = r * 32 + wave * 8 + srow;
            int c   = slot ^ (row & 7);
            const ushort* ga = A  + (size_t)(m0 + row) * K + k0 + c * 8;
            const ushort* gb = Bt + (size_t)(n0 + row) * K + k0 + c * 8;
            GLL16(ga, (char*)&As[bufi][0] + r * 4096 + wave * 1024);
            GLL16(gb, (char*)&Bs[bufi][0] + r * 4096 + wave * 1024);
        }
    };

    STAGE(0, 0);
    STAGE(1, 1);
    asm volatile("s_waitcnt vmcnt(8)" ::: "memory");
    __builtin_amdgcn_sched_barrier(0);
    __builtin_amdgcn_s_barrier();

    int cur = 0;
    for (int t = 0; t < nt; ++t) {
        short8 af[2][4], bfr[2][4];
#pragma unroll
        for (int ks = 0; ks < 2; ks++) {
#pragma unroll
            for (int mi = 0; mi < 4; mi++) {
                int row = wm * 64 + mi * 16 + (lane & 15);
                int c   = ks * 4 + (lane >> 4);
                af[ks][mi] = *(const short8*)(&As[cur][0] + row * 64 + (c ^ (row & 7)) * 8);
            }
#pragma unroll
            for (int ni = 0; ni < 4; ni++) {
                int col = wn * 64 + ni * 16 + (lane & 15);
                int c   = ks * 4 + (lane >> 4);
                bfr[ks][ni] = *(const short8*)(&Bs[cur][0] + col * 64 + (c ^ (col & 7)) * 8);
            }
        }
        asm volatile("s_waitcnt lgkmcnt(0)" ::: "memory");
        __builtin_amdgcn_s_barrier();           // buf[cur] now dead for all waves
        __builtin_amdgcn_sched_barrier(0);

        // stage tile t+2 into the dead buffer (only if it exists)
        bool st = (t + 2) < nt;
        if (st) STAGE(t + 2, cur);

        // counted gate: tile t+1's 8 loads landed; t+2's (if any) stay in flight
        if (st) asm volatile("s_waitcnt vmcnt(8)" ::: "memory");
        else    asm volatile("s_waitcnt vmcnt(0)" ::: "memory");
        __builtin_amdgcn_sched_barrier(0);

#pragma unroll
        for (int ks = 0; ks < 2; ks++)
#pragma unroll
            for (int mi = 0; mi < 4; mi++)
#pragma unroll
                for (int ni = 0; ni < 4; ni++)
                    acc[mi][ni] = MFMA32(af[ks][mi], bfr[ks][ni], acc[mi][ni]);

        __builtin_amdgcn_s_barrier();
        __builtin_amdgcn_sched_barrier(0);
        cur ^= 1;
    }

    int r0 = m0 + wm * 64 + (lane >> 4) * 4;
    int c0 = n0 + wn * 64 + (lane & 15);
#pragma unroll
    for (int mi = 0; mi < 4; mi++) {
#pragma unroll
        for (int ni = 0; ni < 4; ni++) {
            int col = c0 + ni * 16;
            if (MASKN && col >= Nn) continue;
#pragma unroll
            for (int r = 0; r < 4; r++) {
                int row = r0 + mi * 16 + r;
                size_t idx = (size_t)row * Nn + col;
                float v = acc[mi][ni][r];
                if constexpr (EPI == 0) {
                    ((float*)Cout)[idx] = v;
                } else if constexpr (EPI == 1) {
                    ((float*)Cout)[idx] = v + bias[col] + ((const float*)resv)[idx];
                } else if constexpr (EPI == 2) {
                    ((ushort*)Cout)[idx] = f2b(gelu_f(v + bias[col]));
                } else if constexpr (EPI == 3) {
                    ((ushort*)Cout)[idx] = f2b(v + bias[col] + ((const float*)resv)[idx]);
                } else if constexpr (EPI == 4) {
                    ((float*)Cout)[idx] = v + bias[col] + b2f(((const ushort*)resv)[idx]);
                } else {
                    // EPI 5: qkv bf16 store; fold softmax scale into q columns.
                    float sv = (col < 96) ? v * 0.102062072615966f : v;  // 96^-0.5
                    ((ushort*)Cout)[idx] = f2b(sv);
                }
            }
        }
    }
}

// ---------------------------------------------------------------------------
// MFMA attention, bf16 qkv input (scale pre-folded into Q by the qkv GEMM).
// Block = (bh, 128-q group); 512 blocks, 256 thr (4 waves), each wave owns
// 2 q-tiles of 16. K staged bf16 [1024][12], V^T bf16 [12][1032] — staging is
// pure uint2 copies now. S^T = mfma16(K,Q); P^T C-layout == B-frag layout.
// Output: ao bf16 [8192][128]; h==0 blocks also zero-fill pad cols 96..127.
// ---------------------------------------------------------------------------
__global__ __launch_bounds__(256) void attn_mfma_kernel(const ushort* __restrict__ qkv,
                                                        ushort* __restrict__ ao) {
    __shared__ ushort Kt[NSEQ * 12];     // [j][d]
    __shared__ ushort VT[12 * 1032];     // [d][j], stride 1032
    int bh = blockIdx.x >> 3, qg = blockIdx.x & 7;
    int b = bh >> 3, h = bh & 7;
    int tid = threadIdx.x;
    const ushort* base = qkv + (size_t)b * NSEQ * (3 * INNER);

    // Pad zero-fill (replaces memset): h==0 blocks own cols 96..127 of their rows.
    if (h == 0) {
        ushort4 z; z.x = 0; z.y = 0; z.z = 0; z.w = 0;
        for (int s = tid; s < 128 * 8; s += 256) {
            int r = s >> 3, c = s & 7;
            *reinterpret_cast<ushort4*>(
                &ao[((size_t)(b * NSEQ + qg * 128 + r)) * 128 + 96 + c * 4]) = z;
        }
    }

#pragma unroll
    for (int i = 0; i < 4; i++) {
        int j = i * 256 + tid;
        const ushort* kp = base + (size_t)j * (3 * INNER) + INNER + h * HEAD_D;
        uint2* kw = (uint2*)(&Kt[j * 12]);
        kw[0] = *(const uint2*)(kp);
        kw[1] = *(const uint2*)(kp + 4);
        kw[2] = *(const uint2*)(kp + 8);
        const ushort* vp = kp + INNER;
        ushort vv[12];
        *(uint2*)(&vv[0]) = *(const uint2*)(vp);
        *(uint2*)(&vv[4]) = *(const uint2*)(vp + 4);
        *(uint2*)(&vv[8]) = *(const uint2*)(vp + 8);
#pragma unroll
        for (int d = 0; d < 12; d++) VT[d * 1032 + j] = vv[d];
    }
    __syncthreads();

    int lane = tid & 63, wave = tid >> 6;
    int qrow = lane & 15, grp = lane >> 4;

    s4b qf[2];
#pragma unroll
    for (int t = 0; t < 2; t++) {
        qf[t] = (s4b)0;
        if (grp < 3) {
            int q = qg * 128 + (wave * 2 + t) * 16 + qrow;
            const ushort* qp = base + (size_t)q * (3 * INNER) + h * HEAD_D + grp * 4;
            uint2 u = *(const uint2*)(qp);
            qf[t] = __builtin_bit_cast(s4b, u);
        }
    }

    floatx4 acc[2] = {};
    float l[2] = {0.f, 0.f};
    int kc = (grp < 3) ? grp : 0;
    int dv = (qrow < 12) ? qrow : 0;
    bool kz = (grp == 3), vz = (qrow >= 12);
    const floatx4 z4 = {};

    for (int jt = 0; jt < 64; jt++) {
        s4b kf = *(const s4b*)(&Kt[(jt * 16 + qrow) * 12 + kc * 4]);
        if (kz) kf = (s4b)0;
        s4b vf = *(const s4b*)(&VT[dv * 1032 + jt * 16 + grp * 4]);
        if (vz) vf = (s4b)0;
#pragma unroll
        for (int t = 0; t < 2; t++) {
            floatx4 st = mfma16(kf, qf[t], z4);
            float p0 = __expf(st[0]), p1 = __expf(st[1]);
            float p2 = __expf(st[2]), p3 = __expf(st[3]);
            l[t] += (p0 + p1) + (p2 + p3);
            uint2 u = make_uint2(pk2(p0, p1), pk2(p2, p3));
            acc[t] = mfma16(vf, __builtin_bit_cast(s4b, u), acc[t]);
        }
    }

#pragma unroll
    for (int t = 0; t < 2; t++) {
        float lt = l[t];
        lt += __shfl_xor(lt, 16);
        lt += __shfl_xor(lt, 32);
        float inv = 1.f / lt;
        if (grp < 3) {
            int q = qg * 128 + (wave * 2 + t) * 16 + qrow;
            ushort4 o;
            o.x = f2b(acc[t][0] * inv);
            o.y = f2b(acc[t][1] * inv);
            o.z = f2b(acc[t][2] * inv);
            o.w = f2b(acc[t][3] * inv);
            *reinterpret_cast<ushort4*>(&ao[(size_t)(b * NSEQ + q) * 128 + h * HEAD_D + grp * 4]) = o;
        }
    }
}

// ---------------------------------------------------------------------------
// Launch
// ---------------------------------------------------------------------------
extern "C" void kernel_launch(void* const* d_in, const int* in_sizes, int n_in,
                              void* d_out, int out_size, void* d_ws, size_t ws_size,
                              hipStream_t stream) {
    const float* inputs = (const float*)d_in[0];
    const float* ln1_g  = (const float*)d_in[3];
    const float* ln1_b  = (const float*)d_in[4];
    const float* w_qkv  = (const float*)d_in[5];
    const float* w_proj = (const float*)d_in[6];
    const float* b_proj = (const float*)d_in[7];
    const float* ln2_g  = (const float*)d_in[8];
    const float* ln2_b  = (const float*)d_in[9];
    const float* w1     = (const float*)d_in[10];
    const float* b1     = (const float*)d_in[11];
    const float* w2     = (const float*)d_in[12];
    const float* b2     = (const float*)d_in[13];
    float* out = (float*)d_out;

    // Workspace layout (bytes):
    //  h_bf    : 8192*768*2   = 12,582,912  @ 0
    //  qkv     : 8192*288*2   =  4,718,592  @ 12,582,912  (bf16, Q pre-scaled)
    //  ao_pad  : 8192*128*2   =  2,097,152  @ 22,020,096  (bf16, K-padded)
    //  wproj_t : 768*128*2    =    196,608  @ 24,117,248
    //  x1      : 8192*768*2   = 12,582,912  @ 25,165,824  (bf16 residual)
    //  m2      : 8192*3072*2  = 50,331,648  @ 50,331,648
    //  wqkv_t  : 384*768*2    =    589,824  @ 100,663,296
    //  w1_t    : 3072*768*2   =  4,718,592  @ 101,253,120
    //  w2_t    : 768*3072*2   =  4,718,592  @ 105,971,712
    char* ws = (char*)d_ws;
    ushort* h_bf    = (ushort*)(ws);
    ushort* qkv     = (ushort*)(ws + 12582912);
    ushort* ao_pad  = (ushort*)(ws + 22020096);
    ushort* wproj_t = (ushort*)(ws + 24117248);
    ushort* x1      = (ushort*)(ws + 25165824);
    ushort* m2      = (ushort*)(ws + 50331648);
    ushort* wqkv_t  = (ushort*)(ws + 100663296);
    ushort* w1_t    = (ushort*)(ws + 101253120);
    ushort* w2_t    = (ushort*)(ws + 105971712);

    // 0) All weight conversions in one launch (4992 blocks of 32x8)
    convt_all_kernel<<<4992, dim3(32, 8), 0, stream>>>(
        w1, w1_t, w2, w2_t, w_qkv, wqkv_t, w_proj, wproj_t);

    // 1) LN1 -> bf16
    ln_f32in_kernel<<<ROWS / 4, 256, 0, stream>>>(inputs, ln1_g, ln1_b, h_bf);
    // 2) qkv = h @ w_qkv -> bf16 (Q cols pre-scaled)  [8192,288] K=768
    gemm_mfma<5, true><<<3 * (ROWS / 128), 256, 0, stream>>>(
        h_bf, wqkv_t, qkv, nullptr, nullptr, ROWS, 3 * INNER, EMB, 3);
    // 3) attention -> ao_pad bf16 [8192,128] (pad cols zeroed by h==0 blocks)
    attn_mfma_kernel<<<512, 256, 0, stream>>>(qkv, ao_pad);
    // 4) x1 = bf16(inputs + ao @ w_proj + b_proj)   [8192,768] K=128(pad)
    gemm_mfma<3, false><<<6 * (ROWS / 128), 256, 0, stream>>>(
        ao_pad, wproj_t, x1, b_proj, inputs, ROWS, EMB, 128, 6);
    // 5) LN2 (bf16 in) -> bf16
    ln_bf16in_kernel<<<ROWS / 4, 256, 0, stream>>>(x1, ln2_g, ln2_b, h_bf);
    // 6) m2 = gelu(h @ w1 + b1) -> bf16   [8192,3072] K=768; grid 24x64=1536
    gemm_mfma<2, false><<<24 * (ROWS / 128), 256, 0, stream>>>(
        h_bf, w1_t, m2, b1, nullptr, ROWS, MLP_DIM, EMB, 24);
    // 7) out = bf16res(x1) + m2 @ w2 + b2 -> fp32   [8192,768] K=3072
    gemm_mfma<4, false><<<6 * (ROWS / 128), 256, 0, stream>>>(
        m2, w2_t, out, b2, x1, ROWS, EMB, MLP_DIM, 6);
}